// Round 4
// baseline (5176.144 us; speedup 1.0000x reference)
//
#include <hip/hip_runtime.h>
#include <hip/hip_bf16.h>

// Problem constants (B,S,C,H,D,P fixed by setup_inputs)
#define BN 8
#define SS 1024
#define CC 512
#define HH 8
#define DD 64
#define PP 16
#define KT 1040          // S + P
#define QCH 64           // query chunk for score materialization
#define NCHUNK (SS/QCH)

typedef __hip_bfloat16 bf16;

__device__ __forceinline__ float b2f(bf16 v){ return __bfloat162float(v); }
__device__ __forceinline__ bf16  f2b(float v){ return __float2bfloat16(v); }

// ---------------------------------------------------------------------------
// K1: per-(n,s) QKV projection. q/k/v[n,h,s,e] = sum_d x[n,s,h,d]*W[e,d]
// One shared weight buffer reused for Wq,Wk,Wv -> static LDS 18.7 KB.
// qf layout (N,H,S,D) bf16; kf/vf layout (N,H,KT,D) bf16, [S,KT) by persist.
// ---------------------------------------------------------------------------
__global__ __launch_bounds__(256) void qkv_kernel(
    const float* __restrict__ x,
    const float* __restrict__ Wq, const float* __restrict__ Wk, const float* __restrict__ Wv,
    bf16* __restrict__ qf, bf16* __restrict__ kf, bf16* __restrict__ vf)
{
    __shared__ float xs[CC];          // 2 KB
    __shared__ float ww[DD*65];       // 16.6 KB (stride 65 kills conflicts)
    const int tid = threadIdx.x;
    const int m = blockIdx.x;         // n*S + s
    const int n = m >> 10, s = m & 1023;

    for (int i = tid; i < CC; i += 256) xs[i] = x[(size_t)m*CC + i];

    for (int w = 0; w < 3; ++w) {
        const float* W = (w == 0) ? Wq : (w == 1) ? Wk : Wv;
        __syncthreads();  // xs ready (w=0) / previous readers done (w>0)
        for (int i = tid; i < DD*DD; i += 256)
            ww[(i >> 6)*65 + (i & 63)] = W[i];
        __syncthreads();
        for (int r = 0; r < 2; ++r) {
            int idx = tid + r*256;
            int h = idx >> 6, e = idx & 63;
            float a = 0.f;
            for (int d = 0; d < 64; ++d) a += xs[h*64 + d] * ww[e*65 + d];
            if (w == 0)
                qf[(((size_t)(n*HH + h))*SS + s)*DD + e] = f2b(a);
            else if (w == 1)
                kf[(((size_t)(n*HH + h))*KT + s)*DD + e] = f2b(a);
            else
                vf[(((size_t)(n*HH + h))*KT + s)*DD + e] = f2b(a);
        }
    }
}

// ---------------------------------------------------------------------------
// K1b: append persistent memory tokens to kf/vf.
// ---------------------------------------------------------------------------
__global__ __launch_bounds__(256) void persist_kernel(
    const float* __restrict__ pk, const float* __restrict__ pv,
    bf16* __restrict__ kf, bf16* __restrict__ vf)
{
    int idx = blockIdx.x*256 + threadIdx.x;   // over N*H*P*D = 65536
    if (idx >= BN*HH*PP*DD) return;
    int d = idx & 63;
    int p = (idx >> 6) & 15;
    int h = (idx >> 10) & 7;
    int n = idx >> 13;
    size_t dst = (((size_t)(n*HH + h))*KT + SS + p)*DD + d;
    size_t src = ((size_t)p*HH + h)*DD + d;   // pk (P,H,D)
    kf[dst] = f2b(pk[src]);
    vf[dst] = f2b(pv[src]);
}

// ---------------------------------------------------------------------------
// K2: raw energy E[n,ql,h,k] = q . k  (bf16 out; raw scores are O(0.2), the
// large ALiBi bias is added later in f32). Tile 64x64. LDS 33.3 KB.
// ---------------------------------------------------------------------------
__global__ __launch_bounds__(256) void energy_kernel(
    const bf16* __restrict__ qf, const bf16* __restrict__ kf,
    bf16* __restrict__ E, int q0)
{
    __shared__ float As[64*65];
    __shared__ float Bs[64*65];
    const int tid = threadIdx.x;
    const int nh = blockIdx.z;           // n*H + h
    const int mt = blockIdx.y;           // q tile within chunk
    const int kt = blockIdx.x;           // key tile (17 tiles, last partial)
    const int k0 = kt*64;
    const bf16* qb = qf + ((size_t)nh*SS + q0 + mt*64)*DD;
    const bf16* kb = kf + (size_t)nh*KT*DD;

    for (int i = tid; i < 64*64; i += 256) {
        int r = i >> 6, d = i & 63;
        As[r*65 + d] = b2f(qb[(size_t)r*64 + d]);
        int kcol = k0 + r;
        Bs[d*65 + r] = (kcol < KT) ? b2f(kb[(size_t)kcol*64 + d]) : 0.f;
    }
    __syncthreads();

    const int tx = tid & 15, ty = tid >> 4;
    float acc[4][4];
    #pragma unroll
    for (int i = 0; i < 4; ++i)
        #pragma unroll
        for (int j = 0; j < 4; ++j) acc[i][j] = 0.f;

    for (int d = 0; d < 64; ++d) {
        float a[4], b[4];
        #pragma unroll
        for (int i = 0; i < 4; ++i) a[i] = As[(ty*4 + i)*65 + d];
        #pragma unroll
        for (int j = 0; j < 4; ++j) b[j] = Bs[d*65 + tx*4 + j];
        #pragma unroll
        for (int i = 0; i < 4; ++i)
            #pragma unroll
            for (int j = 0; j < 4; ++j) acc[i][j] += a[i]*b[j];
    }

    const int n = nh >> 3, h = nh & 7;
    #pragma unroll
    for (int i = 0; i < 4; ++i) {
        int ql = mt*64 + ty*4 + i;       // chunk-local q
        #pragma unroll
        for (int j = 0; j < 4; ++j) {
            int k = k0 + tx*4 + j;
            if (k < KT)
                E[(((size_t)(n*QCH + ql))*HH + h)*KT + k] = f2b(acc[i][j]);
        }
    }
}

// ---------------------------------------------------------------------------
// K3: per-(n,q) row: +ALiBi, th_pre mix, mask, /sqrt(C), softmax, th_post mix
// with 1/l folded. One 33.3 KB score buffer + 9.2 KB reduction scratch
// (total 43.1 KB). LDS tree reductions only.
// Each thread owns key-columns {tid, tid+256, ...}: head-mix is column-local,
// so in-place with no cross-thread hazard.
// ---------------------------------------------------------------------------
__global__ __launch_bounds__(256) void softmax_kernel(
    bf16* __restrict__ E, const int* __restrict__ mask,
    const float* __restrict__ th_pre, const float* __restrict__ th_post, int q0)
{
    __shared__ float A[HH*KT];           // 33.3 KB
    __shared__ float R[256*9];           // 9.2 KB (stride 9 vs bank conflicts)
    __shared__ float thp[64], thq[64];
    __shared__ float mred[8], lred[8];
    const int tid = threadIdx.x;
    const int blk = blockIdx.x;          // n*QCH + ql
    const int n = blk / QCH, ql = blk % QCH;
    const int q = q0 + ql;
    if (tid < 64) { thp[tid] = th_pre[tid]; thq[tid] = th_post[tid]; }
    bf16* Eb = E + (size_t)blk*HH*KT;

    // load raw scores + ALiBi bias (bias applied BEFORE head mixing)
    for (int g = 0; g < 8; ++g) {
        float slope = exp2f(-(float)(g + 1));   // ALIBI_ALPHA=1, START_I=0
        for (int k = tid; k < KT; k += 256) {
            float e = b2f(Eb[g*KT + k]);
            if (k < SS) e -= fabsf((float)(q - k)) * slope;
            A[g*KT + k] = e;
        }
    }
    __syncthreads();   // also covers thp/thq visibility

    // pass 1: th_pre mix + mask + scale, in place; per-thread running max
    const float invs = 0.044194173824159216f; // 1/sqrt(512)
    const int* mrow = mask + (size_t)n*SS*SS + (size_t)q*SS;
    float mx[8];
    #pragma unroll
    for (int h = 0; h < 8; ++h) mx[h] = -3.4e38f;
    for (int k = tid; k < KT; k += 256) {
        float a[8];
        #pragma unroll
        for (int g = 0; g < 8; ++g) a[g] = A[g*KT + k];
        bool dead = (k < SS) && (mrow[k] == 0);
        #pragma unroll
        for (int h = 0; h < 8; ++h) {
            float t = 0.f;
            #pragma unroll
            for (int g = 0; g < 8; ++g) t += thp[h*8 + g] * a[g];
            if (dead) t = -1e4f;
            t *= invs;
            A[h*KT + k] = t;
            mx[h] = fmaxf(mx[h], t);
        }
    }
    // tree max reduction over 256 threads, all 8 heads at once
    #pragma unroll
    for (int h = 0; h < 8; ++h) R[tid*9 + h] = mx[h];
    __syncthreads();
    for (int off = 128; off > 0; off >>= 1) {
        if (tid < off) {
            #pragma unroll
            for (int h = 0; h < 8; ++h)
                R[tid*9 + h] = fmaxf(R[tid*9 + h], R[(tid + off)*9 + h]);
        }
        __syncthreads();
    }
    if (tid < 8) mred[tid] = R[tid];     // row 0
    __syncthreads();

    // pass 2: exp in place; per-thread sums
    float sm[8];
    #pragma unroll
    for (int g = 0; g < 8; ++g) sm[g] = 0.f;
    for (int k = tid; k < KT; k += 256) {
        #pragma unroll
        for (int g = 0; g < 8; ++g) {
            float e = expf(A[g*KT + k] - mred[g]);
            A[g*KT + k] = e;
            sm[g] += e;
        }
    }
    #pragma unroll
    for (int g = 0; g < 8; ++g) R[tid*9 + g] = sm[g];
    __syncthreads();
    for (int off = 128; off > 0; off >>= 1) {
        if (tid < off) {
            #pragma unroll
            for (int g = 0; g < 8; ++g)
                R[tid*9 + g] += R[(tid + off)*9 + g];
        }
        __syncthreads();
    }
    if (tid < 8) lred[tid] = 1.0f / R[tid];
    __syncthreads();

    // pass 3: th_post mix with 1/l folded; write probs (bf16) to E in place
    for (int k = tid; k < KT; k += 256) {
        float e[8];
        #pragma unroll
        for (int g = 0; g < 8; ++g) e[g] = A[g*KT + k] * lred[g];
        #pragma unroll
        for (int h = 0; h < 8; ++h) {
            float t = 0.f;
            #pragma unroll
            for (int g = 0; g < 8; ++g) t += thq[h*8 + g] * e[g];
            Eb[h*KT + k] = f2b(t);
        }
    }
}

// ---------------------------------------------------------------------------
// K4: AO[n, q, h*64+d] = sum_k probs[n,ql,h,k] * vf[n,h,k,d].  LDS 24.4 KB.
// ---------------------------------------------------------------------------
__global__ __launch_bounds__(256) void pv_kernel(
    const bf16* __restrict__ P, const bf16* __restrict__ vf,
    bf16* __restrict__ AO, int q0)
{
    __shared__ float Ps[32*65];
    __shared__ float Vs[64*65];
    const int tid = threadIdx.x;
    const int nh = blockIdx.y;
    const int n = nh >> 3, h = nh & 7;
    const int qb = blockIdx.x * 32;      // chunk-local
    const bf16* vb = vf + (size_t)nh*KT*DD;
    const int c = tid & 63, rg = tid >> 6;
    float acc[8] = {0,0,0,0,0,0,0,0};

    for (int kt = 0; kt < 17; ++kt) {
        int k0 = kt*64;
        for (int i = tid; i < 32*64; i += 256) {
            int r = i >> 6, kk = i & 63;
            int k = k0 + kk;
            Ps[r*65 + kk] = (k < KT)
                ? b2f(P[(((size_t)(n*QCH + qb + r))*HH + h)*KT + k]) : 0.f;
        }
        for (int i = tid; i < 64*64; i += 256) {
            int r = i >> 6, d = i & 63;
            int k = k0 + r;
            Vs[r*65 + d] = (k < KT) ? b2f(vb[(size_t)k*64 + d]) : 0.f;
        }
        __syncthreads();
        for (int kk = 0; kk < 64; ++kk) {
            float vv = Vs[kk*65 + c];
            #pragma unroll
            for (int rr = 0; rr < 8; ++rr)
                acc[rr] += Ps[(rg + rr*4)*65 + kk] * vv;
        }
        __syncthreads();
    }
    #pragma unroll
    for (int rr = 0; rr < 8; ++rr) {
        int qg = q0 + qb + rg + rr*4;
        AO[((size_t)(n*SS) + qg)*CC + h*64 + c] = f2b(acc[rr]);
    }
}

// ---------------------------------------------------------------------------
// K5: xres = x + AO @ fc_w^T + fc_b.  GEMM M=8192, N=512, K=512. LDS 8.5 KB.
// ---------------------------------------------------------------------------
__global__ __launch_bounds__(256) void fc_kernel(
    const bf16* __restrict__ A, const float* __restrict__ W,
    const float* __restrict__ bias, const float* __restrict__ x,
    bf16* __restrict__ out)
{
    __shared__ float As[64*17];
    __shared__ float Bs[16*65];
    const int tid = threadIdx.x;
    const int c0 = blockIdx.x * 64;
    const int m0 = blockIdx.y * 64;
    const int tx = tid & 15, ty = tid >> 4;
    float acc[4][4];
    #pragma unroll
    for (int i = 0; i < 4; ++i)
        #pragma unroll
        for (int j = 0; j < 4; ++j) acc[i][j] = 0.f;

    for (int kt = 0; kt < CC; kt += 16) {
        for (int i = tid; i < 64*16; i += 256) {
            int r = i >> 4, kk = i & 15;
            As[r*17 + kk] = b2f(A[(size_t)(m0 + r)*CC + kt + kk]);
        }
        for (int i = tid; i < 16*64; i += 256) {
            int cc = i >> 4, kk = i & 15;
            Bs[kk*65 + cc] = W[(size_t)(c0 + cc)*CC + kt + kk];  // W[c, j]
        }
        __syncthreads();
        #pragma unroll
        for (int kk = 0; kk < 16; ++kk) {
            float a[4], b[4];
            #pragma unroll
            for (int i = 0; i < 4; ++i) a[i] = As[(ty*4 + i)*17 + kk];
            #pragma unroll
            for (int j = 0; j < 4; ++j) b[j] = Bs[kk*65 + tx*4 + j];
            #pragma unroll
            for (int i = 0; i < 4; ++i)
                #pragma unroll
                for (int j = 0; j < 4; ++j) acc[i][j] += a[i]*b[j];
        }
        __syncthreads();
    }
    #pragma unroll
    for (int i = 0; i < 4; ++i) {
        int m = m0 + ty*4 + i;
        #pragma unroll
        for (int j = 0; j < 4; ++j) {
            int cj = c0 + tx*4 + j;
            out[(size_t)m*CC + cj] =
                f2b(acc[i][j] + bias[cj] + x[(size_t)m*CC + cj]);
        }
    }
}

// ---------------------------------------------------------------------------
// K6: causal conv (k=3, left pad 2) as GEMM M=8192, N=512, K=1536. LDS 8.5 KB.
// ---------------------------------------------------------------------------
__global__ __launch_bounds__(256) void conv_kernel(
    const bf16* __restrict__ A, const float* __restrict__ W,
    const float* __restrict__ bias, bf16* __restrict__ out)
{
    __shared__ float As[64*17];
    __shared__ float Bs[16*65];
    const int tid = threadIdx.x;
    const int o0 = blockIdx.x * 64;
    const int m0 = blockIdx.y * 64;
    const int tx = tid & 15, ty = tid >> 4;
    float acc[4][4];
    #pragma unroll
    for (int i = 0; i < 4; ++i)
        #pragma unroll
        for (int j = 0; j < 4; ++j) acc[i][j] = 0.f;

    for (int kt = 0; kt < 3*CC; kt += 16) {
        for (int i = tid; i < 64*16; i += 256) {
            int r = i >> 4, kk = i & 15;
            int kg = kt + kk;
            int dk = kg >> 9, ci = kg & 511;
            int m = m0 + r;
            int s = m & (SS - 1);
            int sp = s + dk - 2;
            As[r*17 + kk] = (sp >= 0) ? b2f(A[(size_t)(m + dk - 2)*CC + ci]) : 0.f;
        }
        for (int i = tid; i < 16*64; i += 256) {
            int oo = i >> 4, kk = i & 15;
            int kg = kt + kk;
            int dk = kg >> 9, ci = kg & 511;
            Bs[kk*65 + oo] = W[((size_t)(o0 + oo)*CC + ci)*3 + dk];
        }
        __syncthreads();
        #pragma unroll
        for (int kk = 0; kk < 16; ++kk) {
            float a[4], b[4];
            #pragma unroll
            for (int i = 0; i < 4; ++i) a[i] = As[(ty*4 + i)*17 + kk];
            #pragma unroll
            for (int j = 0; j < 4; ++j) b[j] = Bs[kk*65 + tx*4 + j];
            #pragma unroll
            for (int i = 0; i < 4; ++i)
                #pragma unroll
                for (int j = 0; j < 4; ++j) acc[i][j] += a[i]*b[j];
        }
        __syncthreads();
    }
    #pragma unroll
    for (int i = 0; i < 4; ++i) {
        int m = m0 + ty*4 + i;
        #pragma unroll
        for (int j = 0; j < 4; ++j) {
            int oj = o0 + tx*4 + j;
            float v = acc[i][j] + bias[oj];
            out[(size_t)m*CC + oj] = f2b(fmaxf(v, 0.f));
        }
    }
}

// ---------------------------------------------------------------------------
// K7: out = LN(relu(c2 + xres) masked) * g + b.  f32 output.  LDS 1 KB.
// ---------------------------------------------------------------------------
__global__ __launch_bounds__(256) void final_kernel(
    const bf16* __restrict__ c2, const bf16* __restrict__ xres,
    const int* __restrict__ mask, const float* __restrict__ g,
    const float* __restrict__ b, float* __restrict__ out)
{
    __shared__ float red[256];
    const int tid = threadIdx.x;
    const int m = blockIdx.x;
    const int n = m >> 10, s = m & 1023;
    const int mk = mask[(size_t)n*SS*SS + (size_t)s*SS];   // mask[n,0,s,0]

    float v0 = fmaxf(b2f(c2[(size_t)m*CC + tid])       + b2f(xres[(size_t)m*CC + tid]),       0.f);
    float v1 = fmaxf(b2f(c2[(size_t)m*CC + tid + 256]) + b2f(xres[(size_t)m*CC + tid + 256]), 0.f);
    if (mk == 0) { v0 = 0.f; v1 = 0.f; }

    red[tid] = v0 + v1;
    __syncthreads();
    for (int off = 128; off > 0; off >>= 1) {
        if (tid < off) red[tid] += red[tid + off];
        __syncthreads();
    }
    float mu = red[0] * (1.0f/512.0f);
    __syncthreads();
    float d0 = v0 - mu, d1 = v1 - mu;
    red[tid] = d0*d0 + d1*d1;
    __syncthreads();
    for (int off = 128; off > 0; off >>= 1) {
        if (tid < off) red[tid] += red[tid + off];
        __syncthreads();
    }
    float rstd = rsqrtf(red[0] * (1.0f/512.0f) + 1e-5f);
    out[(size_t)m*CC + tid]       = d0*rstd*g[tid]       + b[tid];
    out[(size_t)m*CC + tid + 256] = d1*rstd*g[tid + 256] + b[tid + 256];
}

// ---------------------------------------------------------------------------
extern "C" void kernel_launch(void* const* d_in, const int* in_sizes, int n_in,
                              void* d_out, int out_size, void* d_ws, size_t ws_size,
                              hipStream_t stream)
{
    const float* x      = (const float*)d_in[0];
    const int*   mask   = (const int*)  d_in[1];
    const float* Wq     = (const float*)d_in[2];
    const float* Wk     = (const float*)d_in[3];
    const float* Wv     = (const float*)d_in[4];
    const float* pk     = (const float*)d_in[5];
    const float* pv     = (const float*)d_in[6];
    const float* th_pre = (const float*)d_in[7];
    const float* th_post= (const float*)d_in[8];
    const float* fc_w   = (const float*)d_in[9];
    const float* fc_b   = (const float*)d_in[10];
    const float* c1w    = (const float*)d_in[11];
    const float* c1b    = (const float*)d_in[12];
    const float* c2w    = (const float*)d_in[13];
    const float* c2b    = (const float*)d_in[14];
    const float* lng    = (const float*)d_in[15];
    const float* lnb    = (const float*)d_in[16];
    float* out = (float*)d_out;
    (void)in_sizes; (void)n_in; (void)out_size; (void)ws_size;

    char* ws = (char*)d_ws;
    const size_t SZ_Q = (size_t)BN*HH*SS*DD*2;   // 8,388,608 B
    const size_t SZ_K = (size_t)BN*HH*KT*DD*2;   // 8,519,680 B
    const size_t SZ_E = (size_t)BN*QCH*HH*KT*2;  // 8,519,680 B (QCH=64)

    bf16* qf = (bf16*)(ws);
    bf16* kf = (bf16*)(ws + SZ_Q);
    bf16* vf = (bf16*)(ws + SZ_Q + SZ_K);
    bf16* E  = (bf16*)(ws + SZ_Q + 2*SZ_K);
    bf16* AO = (bf16*)(ws + SZ_Q + 2*SZ_K + SZ_E);
    // Aliases (regions dead when these are first written):
    bf16* xres = qf;   // qf last read by last energy_kernel; fc writes after
    bf16* h1   = kf;   // kf last read by last energy_kernel
    bf16* c2   = vf;   // vf last read by last pv_kernel
    // total workspace: 8.39 + 8.52 + 8.52 + 8.52 + 8.39 = 42.34 MB

    qkv_kernel<<<BN*SS, 256, 0, stream>>>(x, Wq, Wk, Wv, qf, kf, vf);
    persist_kernel<<<(BN*HH*PP*DD + 255)/256, 256, 0, stream>>>(pk, pv, kf, vf);

    for (int ch = 0; ch < NCHUNK; ++ch) {
        int q0 = ch * QCH;
        energy_kernel<<<dim3((KT + 63)/64, QCH/64, BN*HH), 256, 0, stream>>>(qf, kf, E, q0);
        softmax_kernel<<<BN*QCH, 256, 0, stream>>>(E, mask, th_pre, th_post, q0);
        pv_kernel<<<dim3(QCH/32, BN*HH), 256, 0, stream>>>(E, vf, AO, q0);
    }

    fc_kernel<<<dim3(CC/64, BN*SS/64), 256, 0, stream>>>(AO, fc_w, fc_b, x, xres);
    conv_kernel<<<dim3(CC/64, BN*SS/64), 256, 0, stream>>>(xres, c1w, c1b, h1);
    conv_kernel<<<dim3(CC/64, BN*SS/64), 256, 0, stream>>>(h1, c2w, c2b, c2);
    final_kernel<<<BN*SS, 256, 0, stream>>>(c2, xres, mask, lng, lnb, out);
}

// Round 5
// 1259.876 us; speedup vs baseline: 4.1085x; 4.1085x over previous
//
#include <hip/hip_runtime.h>
#include <hip/hip_bf16.h>

#define BN 8
#define SS 1024
#define CC 512
#define HH 8
#define DD 64
#define PP 16
#define KT 1040
#define QCH 64
#define NCHUNK (SS/QCH)

typedef __hip_bfloat16 bf16;
typedef __attribute__((ext_vector_type(8))) short short8;
typedef __attribute__((ext_vector_type(4))) float f32x4;

__device__ __forceinline__ float b2f(bf16 v){ return __bfloat162float(v); }
__device__ __forceinline__ short f2s(float v){ bf16 b = __float2bfloat16(v); return *(short*)&b; }
__device__ __forceinline__ float s2f(short s){ bf16 b; *(short*)&b = s; return __bfloat162float(b); }

#define MFMA16(a,b,c) __builtin_amdgcn_mfma_f32_16x16x32_bf16(a,b,c,0,0,0)

// ---------------------------------------------------------------------------
// P0: weight pre-conversion to bf16 NT layouts.
// Bfc[c][k]=fc_w[c][k]; Bc[o][dk*512+ci]=cw[o][ci][dk]; Bqkv[w*64+e][d]=W_w[e][d]
// ---------------------------------------------------------------------------
__global__ __launch_bounds__(256) void prep_kernel(
    const float* __restrict__ fc_w, const float* __restrict__ c1w,
    const float* __restrict__ c2w, const float* __restrict__ Wq,
    const float* __restrict__ Wk, const float* __restrict__ Wv,
    short* __restrict__ Bfc, short* __restrict__ Bc1,
    short* __restrict__ Bc2, short* __restrict__ Bqkv)
{
    int i = blockIdx.x*256 + threadIdx.x;
    const int NFC = 512*512, NCV = 512*1536, NQ = 3*64*64;
    if (i < NFC) { Bfc[i] = f2s(fc_w[i]); return; }
    i -= NFC;
    if (i < NCV) {
        int o = i/1536, r = i%1536, dk = r>>9, ci = r&511;
        Bc1[i] = f2s(c1w[(o*512+ci)*3+dk]); return;
    }
    i -= NCV;
    if (i < NCV) {
        int o = i/1536, r = i%1536, dk = r>>9, ci = r&511;
        Bc2[i] = f2s(c2w[(o*512+ci)*3+dk]); return;
    }
    i -= NCV;
    if (i < NQ) {
        int w = i >> 12, rest = i & 4095;
        const float* W = (w==0)?Wq:(w==1)?Wk:Wv;
        Bqkv[i] = f2s(W[((rest>>6)&63)*64 + (rest&63)]);  // [e][d] as-is
    }
}

// ---------------------------------------------------------------------------
// K1: QKV projection, MFMA. Per (head, m-tile64): C[m][e'] = X_h[m][d]*Bqkv[e'][d]
// ---------------------------------------------------------------------------
__global__ __launch_bounds__(256) void qkv_mfma(
    const float* __restrict__ x, const short* __restrict__ Bqkv,
    short* __restrict__ qf, short* __restrict__ kf, short* __restrict__ vf)
{
    __shared__ short Xs[64*72];
    __shared__ short Ws[192*72];
    const int tid = threadIdx.x;
    const int m0 = blockIdx.x * 64;
    const int h = blockIdx.y;
    const int wave = tid >> 6, lane = tid & 63;
    const int lr = lane & 15, lq = lane >> 4;

    for (int i = tid; i < 1024; i += 256) {        // X: 64 rows x 64 d (f32->bf16)
        int r = i >> 4, cg = (i & 15)*4;
        float4 v = *(const float4*)(x + (size_t)(m0+r)*CC + h*64 + cg);
        Xs[r*72+cg+0] = f2s(v.x); Xs[r*72+cg+1] = f2s(v.y);
        Xs[r*72+cg+2] = f2s(v.z); Xs[r*72+cg+3] = f2s(v.w);
    }
    for (int i = tid; i < 3072; i += 256) {        // W: 192 rows x 64 d
        int r = i >> 4, cg = (i & 15)*4;
        *(short4*)(Ws + r*72 + cg) = *(const short4*)(Bqkv + (size_t)r*64 + cg);
    }
    __syncthreads();

    f32x4 acc[12];
    #pragma unroll
    for (int nt = 0; nt < 12; ++nt) acc[nt] = {0.f,0.f,0.f,0.f};
    #pragma unroll
    for (int ks = 0; ks < 2; ++ks) {
        int ko = ks*32 + lq*8;
        short8 a = *(const short8*)(Xs + (wave*16 + lr)*72 + ko);
        #pragma unroll
        for (int nt = 0; nt < 12; ++nt) {
            short8 b = *(const short8*)(Ws + (nt*16 + lr)*72 + ko);
            acc[nt] = MFMA16(a, b, acc[nt]);
        }
    }
    #pragma unroll
    for (int nt = 0; nt < 12; ++nt) {
        int ep = nt*16 + lr;              // e' = w*64+e
        int w = ep >> 6, e = ep & 63;
        #pragma unroll
        for (int reg = 0; reg < 4; ++reg) {
            int m = m0 + wave*16 + lq*4 + reg;
            int n = m >> 10, s = m & 1023;
            short v = f2s(acc[nt][reg]);
            if (w == 0)      qf[(((size_t)(n*HH+h))*SS + s)*DD + e] = v;
            else if (w == 1) kf[(((size_t)(n*HH+h))*KT + s)*DD + e] = v;
            else             vf[(((size_t)(n*HH+h))*KT + s)*DD + e] = v;
        }
    }
}

// ---------------------------------------------------------------------------
// K1b: persistent tokens -> kf/vf tail.
// ---------------------------------------------------------------------------
__global__ __launch_bounds__(256) void persist_kernel(
    const float* __restrict__ pk, const float* __restrict__ pv,
    short* __restrict__ kf, short* __restrict__ vf)
{
    int idx = blockIdx.x*256 + threadIdx.x;
    if (idx >= BN*HH*PP*DD) return;
    int d = idx & 63, p = (idx >> 6) & 15, h = (idx >> 10) & 7, n = idx >> 13;
    size_t dst = (((size_t)(n*HH+h))*KT + SS + p)*DD + d;
    size_t src = ((size_t)p*HH + h)*DD + d;
    kf[dst] = f2s(pk[src]);
    vf[dst] = f2s(pv[src]);
}

// ---------------------------------------------------------------------------
// K2: energy, MFMA NT. Per (n,h,ktile): E[ql][kcol] = q . k
// ---------------------------------------------------------------------------
__global__ __launch_bounds__(256) void energy_mfma(
    const short* __restrict__ qf, const short* __restrict__ kf,
    short* __restrict__ E, int q0)
{
    __shared__ short Qs[64*72];
    __shared__ short Ks[64*72];
    const int tid = threadIdx.x;
    const int kt = blockIdx.x;           // 0..16
    const int nh = blockIdx.z;
    const int wave = tid >> 6, lane = tid & 63;
    const int lr = lane & 15, lq = lane >> 4;

    for (int i = tid; i < 1024; i += 256) {
        int r = i >> 4, cg = (i & 15)*4;
        *(short4*)(Qs + r*72 + cg) =
            *(const short4*)(qf + ((size_t)nh*SS + q0 + r)*DD + cg);
        int kcol = kt*64 + r;
        short4 kv = {0,0,0,0};
        if (kcol < KT) kv = *(const short4*)(kf + ((size_t)nh*KT + kcol)*DD + cg);
        *(short4*)(Ks + r*72 + cg) = kv;
    }
    __syncthreads();

    f32x4 acc[4];
    #pragma unroll
    for (int nt = 0; nt < 4; ++nt) acc[nt] = {0.f,0.f,0.f,0.f};
    #pragma unroll
    for (int ks = 0; ks < 2; ++ks) {
        int ko = ks*32 + lq*8;
        short8 a = *(const short8*)(Qs + (wave*16 + lr)*72 + ko);
        #pragma unroll
        for (int nt = 0; nt < 4; ++nt) {
            short8 b = *(const short8*)(Ks + (nt*16 + lr)*72 + ko);
            acc[nt] = MFMA16(a, b, acc[nt]);
        }
    }
    const int n = nh >> 3, h = nh & 7;
    #pragma unroll
    for (int nt = 0; nt < 4; ++nt) {
        int kcol = kt*64 + nt*16 + lr;
        if (kcol >= KT) continue;
        #pragma unroll
        for (int reg = 0; reg < 4; ++reg) {
            int ql = wave*16 + lq*4 + reg;
            E[(((size_t)(n*QCH + ql))*HH + h)*KT + kcol] = f2s(acc[nt][reg]);
        }
    }
}

// ---------------------------------------------------------------------------
// K3: softmax row block: read E + ALiBi, th_pre mix, mask, scale, softmax,
// th_post mix (1/l folded) -> E in place.
// ---------------------------------------------------------------------------
__global__ __launch_bounds__(256) void softmax_kernel(
    short* __restrict__ E, const int* __restrict__ mask,
    const float* __restrict__ th_pre, const float* __restrict__ th_post, int q0)
{
    __shared__ float A[HH*KT];           // 33.3 KB
    __shared__ float R[256*9];           // 9.2 KB
    __shared__ float thp[64], thq[64];
    __shared__ float mred[8], lred[8];
    const int tid = threadIdx.x;
    const int blk = blockIdx.x;
    const int n = blk / QCH, ql = blk % QCH;
    const int q = q0 + ql;
    if (tid < 64) { thp[tid] = th_pre[tid]; thq[tid] = th_post[tid]; }
    __syncthreads();
    short* Eb = E + (size_t)blk*HH*KT;

    const float sl[8] = {0.5f,0.25f,0.125f,0.0625f,
                         0.03125f,0.015625f,0.0078125f,0.00390625f};
    const float invs = 0.044194173824159216f; // 1/sqrt(512)
    const int* mrow = mask + (size_t)n*SS*SS + (size_t)q*SS;

    float mx[8];
    #pragma unroll
    for (int h = 0; h < 8; ++h) mx[h] = -3.4e38f;
    for (int k = tid; k < KT; k += 256) {
        float dist = (k < SS) ? fabsf((float)(q - k)) : 0.f;
        bool dead = (k < SS) && (mrow[k] == 0);
        float a[8];
        #pragma unroll
        for (int g = 0; g < 8; ++g) a[g] = s2f(Eb[g*KT + k]) - dist*sl[g];
        #pragma unroll
        for (int h = 0; h < 8; ++h) {
            float t = 0.f;
            #pragma unroll
            for (int g = 0; g < 8; ++g) t += thp[h*8 + g]*a[g];
            if (dead) t = -1e4f;
            t *= invs;
            A[h*KT + k] = t;
            mx[h] = fmaxf(mx[h], t);
        }
    }
    #pragma unroll
    for (int h = 0; h < 8; ++h) R[tid*9 + h] = mx[h];
    __syncthreads();
    for (int off = 128; off > 0; off >>= 1) {
        if (tid < off) {
            #pragma unroll
            for (int h = 0; h < 8; ++h)
                R[tid*9 + h] = fmaxf(R[tid*9 + h], R[(tid+off)*9 + h]);
        }
        __syncthreads();
    }
    if (tid < 8) mred[tid] = R[tid];
    __syncthreads();

    float sm[8];
    #pragma unroll
    for (int g = 0; g < 8; ++g) sm[g] = 0.f;
    for (int k = tid; k < KT; k += 256) {
        #pragma unroll
        for (int g = 0; g < 8; ++g) {
            float e = __expf(A[g*KT + k] - mred[g]);
            A[g*KT + k] = e;
            sm[g] += e;
        }
    }
    #pragma unroll
    for (int g = 0; g < 8; ++g) R[tid*9 + g] = sm[g];
    __syncthreads();
    for (int off = 128; off > 0; off >>= 1) {
        if (tid < off) {
            #pragma unroll
            for (int g = 0; g < 8; ++g)
                R[tid*9 + g] += R[(tid+off)*9 + g];
        }
        __syncthreads();
    }
    if (tid < 8) lred[tid] = 1.0f / R[tid];
    __syncthreads();

    for (int k = tid; k < KT; k += 256) {
        float e[8];
        #pragma unroll
        for (int g = 0; g < 8; ++g) e[g] = A[g*KT + k]*lred[g];
        #pragma unroll
        for (int h = 0; h < 8; ++h) {
            float t = 0.f;
            #pragma unroll
            for (int g = 0; g < 8; ++g) t += thq[h*8 + g]*e[g];
            Eb[h*KT + k] = f2s(t);
        }
    }
}

// ---------------------------------------------------------------------------
// K4: PV, MFMA NT. Per (n,h, qtile16): AO[q][h*64+d] = sum_k P[q][k]*V[k][d].
// V transposed into LDS at staging (Bt[d][k]).
// ---------------------------------------------------------------------------
__global__ __launch_bounds__(256) void pv_mfma(
    const short* __restrict__ E, const short* __restrict__ vf,
    short* __restrict__ AO, int q0)
{
    __shared__ short Ps[16*72];
    __shared__ short Vt[64*72];
    const int tid = threadIdx.x;
    const int ql0 = blockIdx.x * 16;
    const int nh = blockIdx.y;
    const int n = nh >> 3, h = nh & 7;
    const int wave = tid >> 6, lane = tid & 63;
    const int lr = lane & 15, lq = lane >> 4;

    f32x4 acc = {0.f,0.f,0.f,0.f};
    for (int kt = 0; kt < 17; ++kt) {
        for (int i = tid; i < 256; i += 256) {       // P: 16 q x 64 k
            int r = i >> 4, cg = (i & 15)*4;
            int k = kt*64 + cg;
            short4 v = {0,0,0,0};
            if (k < KT)
                v = *(const short4*)(E + (((size_t)(n*QCH + ql0 + r))*HH + h)*KT + k);
            *(short4*)(Ps + r*72 + cg) = v;
        }
        for (int i = tid; i < 1024; i += 256) {      // V-tile transpose: Vt[d][k]
            int kk = i >> 4, dg = (i & 15)*4;
            int k = kt*64 + kk;
            short4 v = {0,0,0,0};
            if (k < KT)
                v = *(const short4*)(vf + ((size_t)nh*KT + k)*DD + dg);
            Vt[(dg+0)*72 + kk] = v.x;
            Vt[(dg+1)*72 + kk] = v.y;
            Vt[(dg+2)*72 + kk] = v.z;
            Vt[(dg+3)*72 + kk] = v.w;
        }
        __syncthreads();
        #pragma unroll
        for (int ks = 0; ks < 2; ++ks) {
            int ko = ks*32 + lq*8;
            short8 a = *(const short8*)(Ps + lr*72 + ko);
            short8 b = *(const short8*)(Vt + (wave*16 + lr)*72 + ko);
            acc = MFMA16(a, b, acc);
        }
        __syncthreads();
    }
    #pragma unroll
    for (int reg = 0; reg < 4; ++reg) {
        int qg = q0 + ql0 + lq*4 + reg;
        AO[((size_t)(n*SS) + qg)*CC + h*64 + wave*16 + lr] = f2s(acc[reg]);
    }
}

// ---------------------------------------------------------------------------
// K5: fc, MFMA NT. xres = x + AO @ fc_w^T + fc_b.
// ---------------------------------------------------------------------------
__global__ __launch_bounds__(256) void fc_mfma(
    const short* __restrict__ A, const short* __restrict__ Bt,
    const float* __restrict__ bias, const float* __restrict__ x,
    short* __restrict__ out)
{
    __shared__ short As[128*72];
    __shared__ short Bs[64*72];
    const int tid = threadIdx.x;
    const int n0 = blockIdx.x * 64;
    const int m0 = blockIdx.y * 128;
    const int wave = tid >> 6, lane = tid & 63;
    const int lr = lane & 15, lq = lane >> 4;

    f32x4 acc[2][4];
    #pragma unroll
    for (int i = 0; i < 2; ++i)
        #pragma unroll
        for (int j = 0; j < 4; ++j) acc[i][j] = {0.f,0.f,0.f,0.f};

    for (int kt = 0; kt < CC; kt += 64) {
        for (int i = tid; i < 2048; i += 256) {
            int r = i >> 4, cg = (i & 15)*4;
            *(short4*)(As + r*72 + cg) =
                *(const short4*)(A + (size_t)(m0+r)*CC + kt + cg);
        }
        for (int i = tid; i < 1024; i += 256) {
            int r = i >> 4, cg = (i & 15)*4;
            *(short4*)(Bs + r*72 + cg) =
                *(const short4*)(Bt + (size_t)(n0+r)*CC + kt + cg);
        }
        __syncthreads();
        #pragma unroll
        for (int ks = 0; ks < 2; ++ks) {
            int ko = ks*32 + lq*8;
            short8 a0 = *(const short8*)(As + (wave*32 + lr)*72 + ko);
            short8 a1 = *(const short8*)(As + (wave*32 + 16 + lr)*72 + ko);
            #pragma unroll
            for (int nt = 0; nt < 4; ++nt) {
                short8 b = *(const short8*)(Bs + (nt*16 + lr)*72 + ko);
                acc[0][nt] = MFMA16(a0, b, acc[0][nt]);
                acc[1][nt] = MFMA16(a1, b, acc[1][nt]);
            }
        }
        __syncthreads();
    }
    #pragma unroll
    for (int mt = 0; mt < 2; ++mt)
        #pragma unroll
        for (int nt = 0; nt < 4; ++nt)
            #pragma unroll
            for (int reg = 0; reg < 4; ++reg) {
                int m = m0 + wave*32 + mt*16 + lq*4 + reg;
                int nn = n0 + nt*16 + lr;
                out[(size_t)m*CC + nn] =
                    f2s(acc[mt][nt][reg] + bias[nn] + x[(size_t)m*CC + nn]);
            }
}

// ---------------------------------------------------------------------------
// K6: causal conv as NT GEMM K=1536 with im2col A staging. relu(acc+bias).
// ---------------------------------------------------------------------------
__global__ __launch_bounds__(256) void conv_mfma(
    const short* __restrict__ A, const short* __restrict__ Bt,
    const float* __restrict__ bias, short* __restrict__ out)
{
    __shared__ short As[128*72];
    __shared__ short Bs[64*72];
    const int tid = threadIdx.x;
    const int n0 = blockIdx.x * 64;
    const int m0 = blockIdx.y * 128;
    const int wave = tid >> 6, lane = tid & 63;
    const int lr = lane & 15, lq = lane >> 4;

    f32x4 acc[2][4];
    #pragma unroll
    for (int i = 0; i < 2; ++i)
        #pragma unroll
        for (int j = 0; j < 4; ++j) acc[i][j] = {0.f,0.f,0.f,0.f};

    for (int kt = 0; kt < 1536; kt += 64) {
        const int shift = (kt >> 9) - 2;       // dk-2, constant per 64-slice
        const int ci0 = kt & 511;
        for (int i = tid; i < 2048; i += 256) {
            int r = i >> 4, cg = (i & 15)*4;
            int m = m0 + r;
            int s = m & 1023;
            short4 v = {0,0,0,0};
            if (s + shift >= 0)
                v = *(const short4*)(A + (size_t)(m + shift)*CC + ci0 + cg);
            *(short4*)(As + r*72 + cg) = v;
        }
        for (int i = tid; i < 1024; i += 256) {
            int r = i >> 4, cg = (i & 15)*4;
            *(short4*)(Bs + r*72 + cg) =
                *(const short4*)(Bt + (size_t)(n0+r)*1536 + kt + cg);
        }
        __syncthreads();
        #pragma unroll
        for (int ks = 0; ks < 2; ++ks) {
            int ko = ks*32 + lq*8;
            short8 a0 = *(const short8*)(As + (wave*32 + lr)*72 + ko);
            short8 a1 = *(const short8*)(As + (wave*32 + 16 + lr)*72 + ko);
            #pragma unroll
            for (int nt = 0; nt < 4; ++nt) {
                short8 b = *(const short8*)(Bs + (nt*16 + lr)*72 + ko);
                acc[0][nt] = MFMA16(a0, b, acc[0][nt]);
                acc[1][nt] = MFMA16(a1, b, acc[1][nt]);
            }
        }
        __syncthreads();
    }
    #pragma unroll
    for (int mt = 0; mt < 2; ++mt)
        #pragma unroll
        for (int nt = 0; nt < 4; ++nt)
            #pragma unroll
            for (int reg = 0; reg < 4; ++reg) {
                int m = m0 + wave*32 + mt*16 + lq*4 + reg;
                int nn = n0 + nt*16 + lr;
                float v = acc[mt][nt][reg] + bias[nn];
                out[(size_t)m*CC + nn] = f2s(fmaxf(v, 0.f));
            }
}

// ---------------------------------------------------------------------------
// K7: out = LN(relu(c2 + xres) masked) * g + b.  f32 out.
// ---------------------------------------------------------------------------
__global__ __launch_bounds__(256) void final_kernel(
    const short* __restrict__ c2, const short* __restrict__ xres,
    const int* __restrict__ mask, const float* __restrict__ g,
    const float* __restrict__ b, float* __restrict__ out)
{
    __shared__ float red[256];
    const int tid = threadIdx.x;
    const int m = blockIdx.x;
    const int n = m >> 10, s = m & 1023;
    const int mk = mask[(size_t)n*SS*SS + (size_t)s*SS];

    float v0 = fmaxf(s2f(c2[(size_t)m*CC + tid])       + s2f(xres[(size_t)m*CC + tid]),       0.f);
    float v1 = fmaxf(s2f(c2[(size_t)m*CC + tid + 256]) + s2f(xres[(size_t)m*CC + tid + 256]), 0.f);
    if (mk == 0) { v0 = 0.f; v1 = 0.f; }

    red[tid] = v0 + v1;
    __syncthreads();
    for (int off = 128; off > 0; off >>= 1) {
        if (tid < off) red[tid] += red[tid + off];
        __syncthreads();
    }
    float mu = red[0] * (1.0f/512.0f);
    __syncthreads();
    float d0 = v0 - mu, d1 = v1 - mu;
    red[tid] = d0*d0 + d1*d1;
    __syncthreads();
    for (int off = 128; off > 0; off >>= 1) {
        if (tid < off) red[tid] += red[tid + off];
        __syncthreads();
    }
    float rstd = rsqrtf(red[0] * (1.0f/512.0f) + 1e-5f);
    out[(size_t)m*CC + tid]       = d0*rstd*g[tid]       + b[tid];
    out[(size_t)m*CC + tid + 256] = d1*rstd*g[tid + 256] + b[tid + 256];
}

// ---------------------------------------------------------------------------
extern "C" void kernel_launch(void* const* d_in, const int* in_sizes, int n_in,
                              void* d_out, int out_size, void* d_ws, size_t ws_size,
                              hipStream_t stream)
{
    const float* x      = (const float*)d_in[0];
    const int*   mask   = (const int*)  d_in[1];
    const float* Wq     = (const float*)d_in[2];
    const float* Wk     = (const float*)d_in[3];
    const float* Wv     = (const float*)d_in[4];
    const float* pk     = (const float*)d_in[5];
    const float* pv     = (const float*)d_in[6];
    const float* th_pre = (const float*)d_in[7];
    const float* th_post= (const float*)d_in[8];
    const float* fc_w   = (const float*)d_in[9];
    const float* fc_b   = (const float*)d_in[10];
    const float* c1w    = (const float*)d_in[11];
    const float* c1b    = (const float*)d_in[12];
    const float* c2w    = (const float*)d_in[13];
    const float* c2b    = (const float*)d_in[14];
    const float* lng    = (const float*)d_in[15];
    const float* lnb    = (const float*)d_in[16];
    float* out = (float*)d_out;
    (void)in_sizes; (void)n_in; (void)out_size; (void)ws_size;

    char* ws = (char*)d_ws;
    const size_t SZ_Q = (size_t)BN*HH*SS*DD*2;    // 8.39 MB
    const size_t SZ_K = (size_t)BN*HH*KT*DD*2;    // 8.52 MB
    const size_t SZ_E = (size_t)BN*QCH*HH*KT*2;   // 8.52 MB
    const size_t SZ_A = (size_t)BN*SS*CC*2;       // 8.39 MB

    short* qf  = (short*)(ws);
    short* kf  = (short*)(ws + SZ_Q);
    short* vf  = (short*)(ws + SZ_Q + SZ_K);
    short* E   = (short*)(ws + SZ_Q + 2*SZ_K);
    short* AO  = (short*)(ws + SZ_Q + 2*SZ_K + SZ_E);
    char*  wend = ws + SZ_Q + 2*SZ_K + SZ_E + SZ_A;
    short* Bfc = (short*)(wend);                          // 512 KB
    short* Bc1 = (short*)(wend + 512*512*2);              // 1.5 MB
    short* Bc2 = (short*)(wend + 512*512*2 + 512*1536*2); // 1.5 MB
    short* Bqkv= (short*)(wend + 512*512*2 + 2*512*1536*2); // 24 KB
    // Aliases (dead regions): xres over qf, h1 over kf, c2 over vf
    short* xres = qf;
    short* h1   = kf;
    short* c2   = vf;
    // total ws: 42.34 MB + 3.55 MB = 45.9 MB

    {
        int total = 512*512 + 2*512*1536 + 3*64*64;
        prep_kernel<<<(total + 255)/256, 256, 0, stream>>>(
            fc_w, c1w, c2w, Wq, Wk, Wv, Bfc, Bc1, Bc2, Bqkv);
    }
    qkv_mfma<<<dim3(BN*SS/64, HH), 256, 0, stream>>>(x, Bqkv, qf, kf, vf);
    persist_kernel<<<(BN*HH*PP*DD + 255)/256, 256, 0, stream>>>(pk, pv, kf, vf);

    for (int ch = 0; ch < NCHUNK; ++ch) {
        int q0 = ch * QCH;
        energy_mfma<<<dim3(17, 1, BN*HH), 256, 0, stream>>>(qf, kf, E, q0);
        softmax_kernel<<<BN*QCH, 256, 0, stream>>>(E, mask, th_pre, th_post, q0);
        pv_mfma<<<dim3(QCH/16, BN*HH), 256, 0, stream>>>(E, vf, AO, q0);
    }

    fc_mfma<<<dim3(CC/64, BN*SS/128), 256, 0, stream>>>(AO, Bfc, fc_b, x, xres);
    conv_mfma<<<dim3(CC/64, BN*SS/128), 256, 0, stream>>>(xres, Bc1, c1b, h1);
    conv_mfma<<<dim3(CC/64, BN*SS/128), 256, 0, stream>>>(h1, Bc2, c2b, c2);
    final_kernel<<<BN*SS, 256, 0, stream>>>(c2, xres, mask, lng, lnb, out);
}

// Round 6
// 612.499 us; speedup vs baseline: 8.4509x; 2.0569x over previous
//
#include <hip/hip_runtime.h>
#include <hip/hip_bf16.h>

#define BN 8
#define SS 1024
#define CC 512
#define HH 8
#define DD 64
#define PP 16
#define KT 1040
#define QCH 128
#define NCHUNK (SS/QCH)

typedef __hip_bfloat16 bf16;
typedef __attribute__((ext_vector_type(8))) short short8;
typedef __attribute__((ext_vector_type(4))) float f32x4;

__device__ __forceinline__ short f2s(float v){ bf16 b = __float2bfloat16(v); return *(short*)&b; }
__device__ __forceinline__ float s2f(short s){ bf16 b; *(short*)&b = s; return __bfloat162float(b); }

#define MFMA16(a,b,c) __builtin_amdgcn_mfma_f32_16x16x32_bf16(a,b,c,0,0,0)

// ---------------------------------------------------------------------------
// P0: weight pre-conversion to bf16 NT layouts.
// ---------------------------------------------------------------------------
__global__ __launch_bounds__(256) void prep_kernel(
    const float* __restrict__ fc_w, const float* __restrict__ c1w,
    const float* __restrict__ c2w, const float* __restrict__ Wq,
    const float* __restrict__ Wk, const float* __restrict__ Wv,
    short* __restrict__ Bfc, short* __restrict__ Bc1,
    short* __restrict__ Bc2, short* __restrict__ Bqkv)
{
    int i = blockIdx.x*256 + threadIdx.x;
    const int NFC = 512*512, NCV = 512*1536, NQ = 3*64*64;
    if (i < NFC) { Bfc[i] = f2s(fc_w[i]); return; }
    i -= NFC;
    if (i < NCV) {
        int o = i/1536, r = i%1536, dk = r>>9, ci = r&511;
        Bc1[i] = f2s(c1w[(o*512+ci)*3+dk]); return;
    }
    i -= NCV;
    if (i < NCV) {
        int o = i/1536, r = i%1536, dk = r>>9, ci = r&511;
        Bc2[i] = f2s(c2w[(o*512+ci)*3+dk]); return;
    }
    i -= NCV;
    if (i < NQ) {
        int w = i >> 12, rest = i & 4095;
        const float* W = (w==0)?Wq:(w==1)?Wk:Wv;
        Bqkv[i] = f2s(W[((rest>>6)&63)*64 + (rest&63)]);
    }
}

// ---------------------------------------------------------------------------
// K1: QKV projection, MFMA.
// ---------------------------------------------------------------------------
__global__ __launch_bounds__(256) void qkv_mfma(
    const float* __restrict__ x, const short* __restrict__ Bqkv,
    short* __restrict__ qf, short* __restrict__ kf, short* __restrict__ vf)
{
    __shared__ short Xs[64*72];
    __shared__ short Ws[192*72];
    const int tid = threadIdx.x;
    const int m0 = blockIdx.x * 64;
    const int h = blockIdx.y;
    const int wave = tid >> 6, lane = tid & 63;
    const int lr = lane & 15, lq = lane >> 4;

    for (int i = tid; i < 1024; i += 256) {
        int r = i >> 4, cg = (i & 15)*4;
        float4 v = *(const float4*)(x + (size_t)(m0+r)*CC + h*64 + cg);
        Xs[r*72+cg+0] = f2s(v.x); Xs[r*72+cg+1] = f2s(v.y);
        Xs[r*72+cg+2] = f2s(v.z); Xs[r*72+cg+3] = f2s(v.w);
    }
    for (int i = tid; i < 3072; i += 256) {
        int r = i >> 4, cg = (i & 15)*4;
        *(short4*)(Ws + r*72 + cg) = *(const short4*)(Bqkv + (size_t)r*64 + cg);
    }
    __syncthreads();

    f32x4 acc[12];
    #pragma unroll
    for (int nt = 0; nt < 12; ++nt) acc[nt] = {0.f,0.f,0.f,0.f};
    #pragma unroll
    for (int ks = 0; ks < 2; ++ks) {
        int ko = ks*32 + lq*8;
        short8 a = *(const short8*)(Xs + (wave*16 + lr)*72 + ko);
        #pragma unroll
        for (int nt = 0; nt < 12; ++nt) {
            short8 b = *(const short8*)(Ws + (nt*16 + lr)*72 + ko);
            acc[nt] = MFMA16(a, b, acc[nt]);
        }
    }
    #pragma unroll
    for (int nt = 0; nt < 12; ++nt) {
        int ep = nt*16 + lr;
        int w = ep >> 6, e = ep & 63;
        #pragma unroll
        for (int reg = 0; reg < 4; ++reg) {
            int m = m0 + wave*16 + lq*4 + reg;
            int n = m >> 10, s = m & 1023;
            short v = f2s(acc[nt][reg]);
            if (w == 0)      qf[(((size_t)(n*HH+h))*SS + s)*DD + e] = v;
            else if (w == 1) kf[(((size_t)(n*HH+h))*KT + s)*DD + e] = v;
            else             vf[(((size_t)(n*HH+h))*KT + s)*DD + e] = v;
        }
    }
}

// ---------------------------------------------------------------------------
// K1b: persistent tokens -> kf/vf tail.
// ---------------------------------------------------------------------------
__global__ __launch_bounds__(256) void persist_kernel(
    const float* __restrict__ pk, const float* __restrict__ pv,
    short* __restrict__ kf, short* __restrict__ vf)
{
    int idx = blockIdx.x*256 + threadIdx.x;
    if (idx >= BN*HH*PP*DD) return;
    int d = idx & 63, p = (idx >> 6) & 15, h = (idx >> 10) & 7, n = idx >> 13;
    size_t dst = (((size_t)(n*HH+h))*KT + SS + p)*DD + d;
    size_t src = ((size_t)p*HH + h)*DD + d;
    kf[dst] = f2s(pk[src]);
    vf[dst] = f2s(pv[src]);
}

// ---------------------------------------------------------------------------
// K1c: global V transpose: vt[nh][d][k] = vf[nh][k][d]  (once).
// ---------------------------------------------------------------------------
__global__ __launch_bounds__(256) void vtrans_kernel(
    const short* __restrict__ vf, short* __restrict__ vt)
{
    __shared__ short Ts[64*65];
    const int tid = threadIdx.x;
    const int k0 = blockIdx.x * 64;
    const int nh = blockIdx.y;
    for (int i = tid; i < 1024; i += 256) {
        int kk = i >> 4, dg = (i & 15)*4;
        int k = k0 + kk;
        short4 v = {0,0,0,0};
        if (k < KT) v = *(const short4*)(vf + ((size_t)nh*KT + k)*DD + dg);
        Ts[(dg+0)*65 + kk] = v.x;
        Ts[(dg+1)*65 + kk] = v.y;
        Ts[(dg+2)*65 + kk] = v.z;
        Ts[(dg+3)*65 + kk] = v.w;
    }
    __syncthreads();
    for (int i = tid; i < 1024; i += 256) {
        int d = i >> 4, kg = (i & 15)*4;
        int k = k0 + kg;
        if (k < KT) {
            short4 o;
            o.x = Ts[d*65 + kg+0]; o.y = Ts[d*65 + kg+1];
            o.z = Ts[d*65 + kg+2]; o.w = Ts[d*65 + kg+3];
            *(short4*)(vt + ((size_t)nh*DD + d)*KT + k) = o;
        }
    }
}

// ---------------------------------------------------------------------------
// K2: energy, MFMA NT. grid (17, QCH/64, BN*HH).
// ---------------------------------------------------------------------------
__global__ __launch_bounds__(256) void energy_mfma(
    const short* __restrict__ qf, const short* __restrict__ kf,
    short* __restrict__ E, int q0)
{
    __shared__ short Qs[64*72];
    __shared__ short Ks[64*72];
    const int tid = threadIdx.x;
    const int kt = blockIdx.x;
    const int mt = blockIdx.y;
    const int nh = blockIdx.z;
    const int wave = tid >> 6, lane = tid & 63;
    const int lr = lane & 15, lq = lane >> 4;

    for (int i = tid; i < 1024; i += 256) {
        int r = i >> 4, cg = (i & 15)*4;
        *(short4*)(Qs + r*72 + cg) =
            *(const short4*)(qf + ((size_t)nh*SS + q0 + mt*64 + r)*DD + cg);
        int kcol = kt*64 + r;
        short4 kv = {0,0,0,0};
        if (kcol < KT) kv = *(const short4*)(kf + ((size_t)nh*KT + kcol)*DD + cg);
        *(short4*)(Ks + r*72 + cg) = kv;
    }
    __syncthreads();

    f32x4 acc[4];
    #pragma unroll
    for (int nt = 0; nt < 4; ++nt) acc[nt] = {0.f,0.f,0.f,0.f};
    #pragma unroll
    for (int ks = 0; ks < 2; ++ks) {
        int ko = ks*32 + lq*8;
        short8 a = *(const short8*)(Qs + (wave*16 + lr)*72 + ko);
        #pragma unroll
        for (int nt = 0; nt < 4; ++nt) {
            short8 b = *(const short8*)(Ks + (nt*16 + lr)*72 + ko);
            acc[nt] = MFMA16(a, b, acc[nt]);
        }
    }
    const int n = nh >> 3, h = nh & 7;
    #pragma unroll
    for (int nt = 0; nt < 4; ++nt) {
        int kcol = kt*64 + nt*16 + lr;
        if (kcol >= KT) continue;
        #pragma unroll
        for (int reg = 0; reg < 4; ++reg) {
            int ql = mt*64 + wave*16 + lq*4 + reg;
            E[(((size_t)(n*QCH + ql))*HH + h)*KT + kcol] = f2s(acc[nt][reg]);
        }
    }
}

// ---------------------------------------------------------------------------
// K3: softmax row block (ALiBi, th_pre, mask, scale, softmax, th_post*1/l).
// ---------------------------------------------------------------------------
__global__ __launch_bounds__(256) void softmax_kernel(
    short* __restrict__ E, const int* __restrict__ mask,
    const float* __restrict__ th_pre, const float* __restrict__ th_post, int q0)
{
    __shared__ float A[HH*KT];
    __shared__ float R[256*9];
    __shared__ float thp[64], thq[64];
    __shared__ float mred[8], lred[8];
    const int tid = threadIdx.x;
    const int blk = blockIdx.x;
    const int n = blk / QCH, ql = blk % QCH;
    const int q = q0 + ql;
    if (tid < 64) { thp[tid] = th_pre[tid]; thq[tid] = th_post[tid]; }
    __syncthreads();
    short* Eb = E + (size_t)blk*HH*KT;

    const float sl[8] = {0.5f,0.25f,0.125f,0.0625f,
                         0.03125f,0.015625f,0.0078125f,0.00390625f};
    const float invs = 0.044194173824159216f;
    const int* mrow = mask + (size_t)n*SS*SS + (size_t)q*SS;

    float mx[8];
    #pragma unroll
    for (int h = 0; h < 8; ++h) mx[h] = -3.4e38f;
    for (int k = tid; k < KT; k += 256) {
        float dist = (k < SS) ? fabsf((float)(q - k)) : 0.f;
        bool dead = (k < SS) && (mrow[k] == 0);
        float a[8];
        #pragma unroll
        for (int g = 0; g < 8; ++g) a[g] = s2f(Eb[g*KT + k]) - dist*sl[g];
        #pragma unroll
        for (int h = 0; h < 8; ++h) {
            float t = 0.f;
            #pragma unroll
            for (int g = 0; g < 8; ++g) t += thp[h*8 + g]*a[g];
            if (dead) t = -1e4f;
            t *= invs;
            A[h*KT + k] = t;
            mx[h] = fmaxf(mx[h], t);
        }
    }
    #pragma unroll
    for (int h = 0; h < 8; ++h) R[tid*9 + h] = mx[h];
    __syncthreads();
    for (int off = 128; off > 0; off >>= 1) {
        if (tid < off) {
            #pragma unroll
            for (int h = 0; h < 8; ++h)
                R[tid*9 + h] = fmaxf(R[tid*9 + h], R[(tid+off)*9 + h]);
        }
        __syncthreads();
    }
    if (tid < 8) mred[tid] = R[tid];
    __syncthreads();

    float sm[8];
    #pragma unroll
    for (int g = 0; g < 8; ++g) sm[g] = 0.f;
    for (int k = tid; k < KT; k += 256) {
        #pragma unroll
        for (int g = 0; g < 8; ++g) {
            float e = __expf(A[g*KT + k] - mred[g]);
            A[g*KT + k] = e;
            sm[g] += e;
        }
    }
    #pragma unroll
    for (int g = 0; g < 8; ++g) R[tid*9 + g] = sm[g];
    __syncthreads();
    for (int off = 128; off > 0; off >>= 1) {
        if (tid < off) {
            #pragma unroll
            for (int g = 0; g < 8; ++g)
                R[tid*9 + g] += R[(tid+off)*9 + g];
        }
        __syncthreads();
    }
    if (tid < 8) lred[tid] = 1.0f / R[tid];
    __syncthreads();

    for (int k = tid; k < KT; k += 256) {
        float e[8];
        #pragma unroll
        for (int g = 0; g < 8; ++g) e[g] = A[g*KT + k]*lred[g];
        #pragma unroll
        for (int h = 0; h < 8; ++h) {
            float t = 0.f;
            #pragma unroll
            for (int g = 0; g < 8; ++g) t += thq[h*8 + g]*e[g];
            Eb[h*KT + k] = f2s(t);
        }
    }
}

// ---------------------------------------------------------------------------
// K4: PV via vt, NT-GEMM, q-tile 32, register-prefetch dbuf.
// ---------------------------------------------------------------------------
__device__ __forceinline__ void pv_loadP(const short* __restrict__ E,
    int n, int h, int ql0, int kt, int tid, short4* rp)
{
    #pragma unroll
    for (int j = 0; j < 2; ++j) {
        int i = tid + j*256;
        int r = i >> 4, cg = (i & 15)*4;
        int k = kt*64 + cg;
        short4 v = {0,0,0,0};
        if (k < KT)
            v = *(const short4*)(E + (((size_t)(n*QCH + ql0 + r))*HH + h)*KT + k);
        rp[j] = v;
    }
}
__device__ __forceinline__ void pv_loadV(const short* __restrict__ vt,
    int nh, int kt, int tid, short4* rv)
{
    #pragma unroll
    for (int j = 0; j < 4; ++j) {
        int i = tid + j*256;
        int r = i >> 4, cg = (i & 15)*4;
        int k = kt*64 + cg;
        short4 v = {0,0,0,0};
        if (k < KT)
            v = *(const short4*)(vt + ((size_t)nh*DD + r)*KT + k);
        rv[j] = v;
    }
}

__global__ __launch_bounds__(256) void pv_mfma(
    const short* __restrict__ E, const short* __restrict__ vt,
    short* __restrict__ AO, int q0)
{
    __shared__ short Ps[32*72];
    __shared__ short Vs[64*72];
    const int tid = threadIdx.x;
    const int ql0 = blockIdx.x * 32;
    const int nh = blockIdx.y;
    const int n = nh >> 3, h = nh & 7;
    const int wave = tid >> 6, lane = tid & 63;
    const int lr = lane & 15, lq = lane >> 4;
    const int mh = wave & 1, nb = (wave >> 1)*32;

    short4 rp[2], rv[4];
    pv_loadP(E, n, h, ql0, 0, tid, rp);
    pv_loadV(vt, nh, 0, tid, rv);

    f32x4 acc[2];
    acc[0] = {0.f,0.f,0.f,0.f}; acc[1] = {0.f,0.f,0.f,0.f};

    for (int kt = 0; kt < 17; ++kt) {
        if (kt) __syncthreads();
        #pragma unroll
        for (int j = 0; j < 2; ++j) {
            int i = tid + j*256;
            *(short4*)(Ps + (i >> 4)*72 + (i & 15)*4) = rp[j];
        }
        #pragma unroll
        for (int j = 0; j < 4; ++j) {
            int i = tid + j*256;
            *(short4*)(Vs + (i >> 4)*72 + (i & 15)*4) = rv[j];
        }
        __syncthreads();
        if (kt + 1 < 17) {
            pv_loadP(E, n, h, ql0, kt+1, tid, rp);
            pv_loadV(vt, nh, kt+1, tid, rv);
        }
        #pragma unroll
        for (int ks = 0; ks < 2; ++ks) {
            int ko = ks*32 + lq*8;
            short8 a = *(const short8*)(Ps + (mh*16 + lr)*72 + ko);
            #pragma unroll
            for (int nt = 0; nt < 2; ++nt) {
                short8 b = *(const short8*)(Vs + (nb + nt*16 + lr)*72 + ko);
                acc[nt] = MFMA16(a, b, acc[nt]);
            }
        }
    }
    #pragma unroll
    for (int nt = 0; nt < 2; ++nt) {
        int d = nb + nt*16 + lr;
        #pragma unroll
        for (int reg = 0; reg < 4; ++reg) {
            int qg = q0 + ql0 + mh*16 + lq*4 + reg;
            AO[((size_t)(n*SS) + qg)*CC + h*64 + d] = f2s(acc[nt][reg]);
        }
    }
}

// ---------------------------------------------------------------------------
// K5: fc, 64x64 tile, XCD-swizzled, register-prefetch dbuf. K=512.
// ---------------------------------------------------------------------------
__device__ __forceinline__ void g_load4(const short* __restrict__ src,
    size_t rowstride, int row0, int col0, int tid, short4* r)
{
    #pragma unroll
    for (int j = 0; j < 4; ++j) {
        int i = tid + j*256;
        int rr = i >> 4, cg = (i & 15)*4;
        r[j] = *(const short4*)(src + (size_t)(row0 + rr)*rowstride + col0 + cg);
    }
}
__device__ __forceinline__ void lds_store4(short* __restrict__ dst,
    int tid, const short4* r)
{
    #pragma unroll
    for (int j = 0; j < 4; ++j) {
        int i = tid + j*256;
        *(short4*)(dst + (i >> 4)*72 + (i & 15)*4) = r[j];
    }
}

__global__ __launch_bounds__(256) void fc_mfma(
    const short* __restrict__ A, const short* __restrict__ Bt,
    const float* __restrict__ bias, const float* __restrict__ x,
    short* __restrict__ out)
{
    __shared__ short As[64*72];
    __shared__ short Bs[64*72];
    const int tid = threadIdx.x;
    const int lin = blockIdx.x + 8*blockIdx.y;      // grid (8,128)
    const int xcd = lin & 7, slot = lin >> 3;
    const int m0 = (xcd*16 + (slot & 15))*64;
    const int n0 = (slot >> 4)*64;
    const int wave = tid >> 6, lane = tid & 63;
    const int lr = lane & 15, lq = lane >> 4;

    short4 ra[4], rb[4];
    g_load4(A, CC, m0, 0, tid, ra);
    g_load4(Bt, CC, n0, 0, tid, rb);

    f32x4 acc[4];
    #pragma unroll
    for (int nt = 0; nt < 4; ++nt) acc[nt] = {0.f,0.f,0.f,0.f};

    for (int kt = 0; kt < CC; kt += 64) {
        if (kt) __syncthreads();
        lds_store4(As, tid, ra);
        lds_store4(Bs, tid, rb);
        __syncthreads();
        if (kt + 64 < CC) {
            g_load4(A, CC, m0, kt+64, tid, ra);
            g_load4(Bt, CC, n0, kt+64, tid, rb);
        }
        #pragma unroll
        for (int ks = 0; ks < 2; ++ks) {
            int ko = ks*32 + lq*8;
            short8 a = *(const short8*)(As + (wave*16 + lr)*72 + ko);
            #pragma unroll
            for (int nt = 0; nt < 4; ++nt) {
                short8 b = *(const short8*)(Bs + (nt*16 + lr)*72 + ko);
                acc[nt] = MFMA16(a, b, acc[nt]);
            }
        }
    }
    #pragma unroll
    for (int nt = 0; nt < 4; ++nt) {
        int nn = n0 + nt*16 + lr;
        #pragma unroll
        for (int reg = 0; reg < 4; ++reg) {
            int m = m0 + wave*16 + lq*4 + reg;
            out[(size_t)m*CC + nn] =
                f2s(acc[nt][reg] + bias[nn] + x[(size_t)m*CC + nn]);
        }
    }
}

// ---------------------------------------------------------------------------
// K6: causal conv as NT GEMM K=1536, 64x64, XCD-swizzled, prefetch dbuf.
// ---------------------------------------------------------------------------
__device__ __forceinline__ void conv_loadA(const short* __restrict__ A,
    int m0, int kt, int tid, short4* ra)
{
    const int shift = (kt >> 9) - 2;
    const int ci0 = kt & 511;
    #pragma unroll
    for (int j = 0; j < 4; ++j) {
        int i = tid + j*256;
        int rr = i >> 4, cg = (i & 15)*4;
        int m = m0 + rr;
        int s = m & (SS-1);
        short4 v = {0,0,0,0};
        if (s + shift >= 0)
            v = *(const short4*)(A + (size_t)(m + shift)*CC + ci0 + cg);
        ra[j] = v;
    }
}

__global__ __launch_bounds__(256) void conv_mfma(
    const short* __restrict__ A, const short* __restrict__ Bt,
    const float* __restrict__ bias, short* __restrict__ out)
{
    __shared__ short As[64*72];
    __shared__ short Bs[64*72];
    const int tid = threadIdx.x;
    const int lin = blockIdx.x + 8*blockIdx.y;      // grid (8,128)
    const int xcd = lin & 7, slot = lin >> 3;
    const int m0 = (xcd*16 + (slot & 15))*64;
    const int n0 = (slot >> 4)*64;
    const int wave = tid >> 6, lane = tid & 63;
    const int lr = lane & 15, lq = lane >> 4;

    short4 ra[4], rb[4];
    conv_loadA(A, m0, 0, tid, ra);
    g_load4(Bt, 1536, n0, 0, tid, rb);

    f32x4 acc[4];
    #pragma unroll
    for (int nt = 0; nt < 4; ++nt) acc[nt] = {0.f,0.f,0.f,0.f};

    for (int kt = 0; kt < 1536; kt += 64) {
        if (kt) __syncthreads();
        lds_store4(As, tid, ra);
        lds_store4(Bs, tid, rb);
        __syncthreads();
        if (kt + 64 < 1536) {
            conv_loadA(A, m0, kt+64, tid, ra);
            g_load4(Bt, 1536, n0, kt+64, tid, rb);
        }
        #pragma unroll
        for (int ks = 0; ks < 2; ++ks) {
            int ko = ks*32 + lq*8;
            short8 a = *(const short8*)(As + (wave*16 + lr)*72 + ko);
            #pragma unroll
            for (int nt = 0; nt < 4; ++nt) {
                short8 b = *(const short8*)(Bs + (nt*16 + lr)*72 + ko);
                acc[nt] = MFMA16(a, b, acc[nt]);
            }
        }
    }
    #pragma unroll
    for (int nt = 0; nt < 4; ++nt) {
        int nn = n0 + nt*16 + lr;
        #pragma unroll
        for (int reg = 0; reg < 4; ++reg) {
            int m = m0 + wave*16 + lq*4 + reg;
            float v = acc[nt][reg] + bias[nn];
            out[(size_t)m*CC + nn] = f2s(fmaxf(v, 0.f));
        }
    }
}

// ---------------------------------------------------------------------------
// K7: out = LN(relu(c2 + xres) masked) * g + b.  f32 out.
// ---------------------------------------------------------------------------
__global__ __launch_bounds__(256) void final_kernel(
    const short* __restrict__ c2, const short* __restrict__ xres,
    const int* __restrict__ mask, const float* __restrict__ g,
    const float* __restrict__ b, float* __restrict__ out)
{
    __shared__ float red[256];
    const int tid = threadIdx.x;
    const int m = blockIdx.x;
    const int n = m >> 10, s = m & 1023;
    const int mk = mask[(size_t)n*SS*SS + (size_t)s*SS];

    float v0 = fmaxf(s2f(c2[(size_t)m*CC + tid])       + s2f(xres[(size_t)m*CC + tid]),       0.f);
    float v1 = fmaxf(s2f(c2[(size_t)m*CC + tid + 256]) + s2f(xres[(size_t)m*CC + tid + 256]), 0.f);
    if (mk == 0) { v0 = 0.f; v1 = 0.f; }

    red[tid] = v0 + v1;
    __syncthreads();
    for (int off = 128; off > 0; off >>= 1) {
        if (tid < off) red[tid] += red[tid + off];
        __syncthreads();
    }
    float mu = red[0] * (1.0f/512.0f);
    __syncthreads();
    float d0 = v0 - mu, d1 = v1 - mu;
    red[tid] = d0*d0 + d1*d1;
    __syncthreads();
    for (int off = 128; off > 0; off >>= 1) {
        if (tid < off) red[tid] += red[tid + off];
        __syncthreads();
    }
    float rstd = rsqrtf(red[0] * (1.0f/512.0f) + 1e-5f);
    out[(size_t)m*CC + tid]       = d0*rstd*g[tid]       + b[tid];
    out[(size_t)m*CC + tid + 256] = d1*rstd*g[tid + 256] + b[tid + 256];
}

// ---------------------------------------------------------------------------
extern "C" void kernel_launch(void* const* d_in, const int* in_sizes, int n_in,
                              void* d_out, int out_size, void* d_ws, size_t ws_size,
                              hipStream_t stream)
{
    const float* x      = (const float*)d_in[0];
    const int*   mask   = (const int*)  d_in[1];
    const float* Wq     = (const float*)d_in[2];
    const float* Wk     = (const float*)d_in[3];
    const float* Wv     = (const float*)d_in[4];
    const float* pk     = (const float*)d_in[5];
    const float* pv     = (const float*)d_in[6];
    const float* th_pre = (const float*)d_in[7];
    const float* th_post= (const float*)d_in[8];
    const float* fc_w   = (const float*)d_in[9];
    const float* fc_b   = (const float*)d_in[10];
    const float* c1w    = (const float*)d_in[11];
    const float* c1b    = (const float*)d_in[12];
    const float* c2w    = (const float*)d_in[13];
    const float* c2b    = (const float*)d_in[14];
    const float* lng    = (const float*)d_in[15];
    const float* lnb    = (const float*)d_in[16];
    float* out = (float*)d_out;
    (void)in_sizes; (void)n_in; (void)out_size; (void)ws_size;

    char* ws = (char*)d_ws;
    const size_t SZ_Q  = (size_t)BN*HH*SS*DD*2;    // 8.39 MB
    const size_t SZ_K  = (size_t)BN*HH*KT*DD*2;    // 8.52 MB
    const size_t SZ_VT = (size_t)BN*HH*DD*KT*2;    // 8.52 MB
    const size_t SZ_E  = (size_t)BN*QCH*HH*KT*2;   // 17.04 MB
    const size_t SZ_A  = (size_t)BN*SS*CC*2;       // 8.39 MB

    short* qf  = (short*)(ws);
    short* kf  = (short*)(ws + SZ_Q);
    short* vf  = (short*)(ws + SZ_Q + SZ_K);
    short* vt  = (short*)(ws + SZ_Q + 2*SZ_K);
    short* E   = (short*)(ws + SZ_Q + 2*SZ_K + SZ_VT);
    short* AO  = (short*)(ws + SZ_Q + 2*SZ_K + SZ_VT + SZ_E);
    char*  wend = ws + SZ_Q + 2*SZ_K + SZ_VT + SZ_E + SZ_A;
    short* Bfc = (short*)(wend);
    short* Bc1 = (short*)(wend + 512*512*2);
    short* Bc2 = (short*)(wend + 512*512*2 + 512*1536*2);
    short* Bqkv= (short*)(wend + 512*512*2 + 2*512*1536*2);
    // Aliases (regions dead when these are first written):
    short* xres = qf;   // qf dead after last energy
    short* h1   = kf;   // kf dead after last energy
    short* c2   = vf;   // vf dead after vtrans (pv uses vt)
    // total ws ~= 63.1 MB

    {
        int total = 512*512 + 2*512*1536 + 3*64*64;
        prep_kernel<<<(total + 255)/256, 256, 0, stream>>>(
            fc_w, c1w, c2w, Wq, Wk, Wv, Bfc, Bc1, Bc2, Bqkv);
    }
    qkv_mfma<<<dim3(BN*SS/64, HH), 256, 0, stream>>>(x, Bqkv, qf, kf, vf);
    persist_kernel<<<(BN*HH*PP*DD + 255)/256, 256, 0, stream>>>(pk, pv, kf, vf);
    vtrans_kernel<<<dim3(17, BN*HH), 256, 0, stream>>>(vf, vt);

    for (int ch = 0; ch < NCHUNK; ++ch) {
        int q0 = ch * QCH;
        energy_mfma<<<dim3(17, QCH/64, BN*HH), 256, 0, stream>>>(qf, kf, E, q0);
        softmax_kernel<<<BN*QCH, 256, 0, stream>>>(E, mask, th_pre, th_post, q0);
        pv_mfma<<<dim3(QCH/32, BN*HH), 256, 0, stream>>>(E, vt, AO, q0);
    }

    fc_mfma<<<dim3(8, 128), 256, 0, stream>>>(AO, Bfc, fc_b, x, xres);
    conv_mfma<<<dim3(8, 128), 256, 0, stream>>>(xres, Bc1, c1b, h1);
    conv_mfma<<<dim3(8, 128), 256, 0, stream>>>(h1, Bc2, c2b, c2);
    final_kernel<<<BN*SS, 256, 0, stream>>>(c2, xres, mask, lng, lnb, out);
}

// Round 7
// 431.555 us; speedup vs baseline: 11.9942x; 1.4193x over previous
//
#include <hip/hip_runtime.h>
#include <hip/hip_bf16.h>

#define BN 8
#define SS 1024
#define CC 512
#define HH 8
#define DD 64
#define PP 16
#define KT 1040

typedef __hip_bfloat16 bf16;
typedef __attribute__((ext_vector_type(8))) short short8;
typedef __attribute__((ext_vector_type(4))) float f32x4;

__device__ __forceinline__ short f2s(float v){ bf16 b = __float2bfloat16(v); return *(short*)&b; }
__device__ __forceinline__ float s2f(short s){ bf16 b; *(short*)&b = s; return __bfloat162float(b); }

#define MFMA16(a,b,c) __builtin_amdgcn_mfma_f32_16x16x32_bf16(a,b,c,0,0,0)

// ---------------------------------------------------------------------------
// P0: weight pre-conversion to bf16 NT layouts.
// ---------------------------------------------------------------------------
__global__ __launch_bounds__(256) void prep_kernel(
    const float* __restrict__ fc_w, const float* __restrict__ c1w,
    const float* __restrict__ c2w, const float* __restrict__ Wq,
    const float* __restrict__ Wk, const float* __restrict__ Wv,
    short* __restrict__ Bfc, short* __restrict__ Bc1,
    short* __restrict__ Bc2, short* __restrict__ Bqkv)
{
    int i = blockIdx.x*256 + threadIdx.x;
    const int NFC = 512*512, NCV = 512*1536, NQ = 3*64*64;
    if (i < NFC) { Bfc[i] = f2s(fc_w[i]); return; }
    i -= NFC;
    if (i < NCV) {
        int o = i/1536, r = i%1536, dk = r>>9, ci = r&511;
        Bc1[i] = f2s(c1w[(o*512+ci)*3+dk]); return;
    }
    i -= NCV;
    if (i < NCV) {
        int o = i/1536, r = i%1536, dk = r>>9, ci = r&511;
        Bc2[i] = f2s(c2w[(o*512+ci)*3+dk]); return;
    }
    i -= NCV;
    if (i < NQ) {
        int w = i >> 12, rest = i & 4095;
        const float* W = (w==0)?Wq:(w==1)?Wk:Wv;
        Bqkv[i] = f2s(W[((rest>>6)&63)*64 + (rest&63)]);
    }
}

// ---------------------------------------------------------------------------
// K1: QKV projection, MFMA.
// ---------------------------------------------------------------------------
__global__ __launch_bounds__(256) void qkv_mfma(
    const float* __restrict__ x, const short* __restrict__ Bqkv,
    short* __restrict__ qf, short* __restrict__ kf, short* __restrict__ vf)
{
    __shared__ short Xs[64*72];
    __shared__ short Ws[192*72];
    const int tid = threadIdx.x;
    const int m0 = blockIdx.x * 64;
    const int h = blockIdx.y;
    const int wave = tid >> 6, lane = tid & 63;
    const int lr = lane & 15, lq = lane >> 4;

    for (int i = tid; i < 1024; i += 256) {
        int r = i >> 4, cg = (i & 15)*4;
        float4 v = *(const float4*)(x + (size_t)(m0+r)*CC + h*64 + cg);
        Xs[r*72+cg+0] = f2s(v.x); Xs[r*72+cg+1] = f2s(v.y);
        Xs[r*72+cg+2] = f2s(v.z); Xs[r*72+cg+3] = f2s(v.w);
    }
    for (int i = tid; i < 3072; i += 256) {
        int r = i >> 4, cg = (i & 15)*4;
        *(short4*)(Ws + r*72 + cg) = *(const short4*)(Bqkv + (size_t)r*64 + cg);
    }
    __syncthreads();

    f32x4 acc[12];
    #pragma unroll
    for (int nt = 0; nt < 12; ++nt) acc[nt] = {0.f,0.f,0.f,0.f};
    #pragma unroll
    for (int ks = 0; ks < 2; ++ks) {
        int ko = ks*32 + lq*8;
        short8 a = *(const short8*)(Xs + (wave*16 + lr)*72 + ko);
        #pragma unroll
        for (int nt = 0; nt < 12; ++nt) {
            short8 b = *(const short8*)(Ws + (nt*16 + lr)*72 + ko);
            acc[nt] = MFMA16(a, b, acc[nt]);
        }
    }
    #pragma unroll
    for (int nt = 0; nt < 12; ++nt) {
        int ep = nt*16 + lr;
        int w = ep >> 6, e = ep & 63;
        #pragma unroll
        for (int reg = 0; reg < 4; ++reg) {
            int m = m0 + wave*16 + lq*4 + reg;
            int n = m >> 10, s = m & 1023;
            short v = f2s(acc[nt][reg]);
            if (w == 0)      qf[(((size_t)(n*HH+h))*SS + s)*DD + e] = v;
            else if (w == 1) kf[(((size_t)(n*HH+h))*KT + s)*DD + e] = v;
            else             vf[(((size_t)(n*HH+h))*KT + s)*DD + e] = v;
        }
    }
}

// ---------------------------------------------------------------------------
// K1b: persistent tokens -> kf/vf tail.
// ---------------------------------------------------------------------------
__global__ __launch_bounds__(256) void persist_kernel(
    const float* __restrict__ pk, const float* __restrict__ pv,
    short* __restrict__ kf, short* __restrict__ vf)
{
    int idx = blockIdx.x*256 + threadIdx.x;
    if (idx >= BN*HH*PP*DD) return;
    int d = idx & 63, p = (idx >> 6) & 15, h = (idx >> 10) & 7, n = idx >> 13;
    size_t dst = (((size_t)(n*HH+h))*KT + SS + p)*DD + d;
    size_t src = ((size_t)p*HH + h)*DD + d;
    kf[dst] = f2s(pk[src]);
    vf[dst] = f2s(pv[src]);
}

// ---------------------------------------------------------------------------
// K1c: global V transpose: vt[nh][d][k] = vf[nh][k][d].
// ---------------------------------------------------------------------------
__global__ __launch_bounds__(256) void vtrans_kernel(
    const short* __restrict__ vf, short* __restrict__ vt)
{
    __shared__ short Ts[64*65];
    const int tid = threadIdx.x;
    const int k0 = blockIdx.x * 64;
    const int nh = blockIdx.y;
    for (int i = tid; i < 1024; i += 256) {
        int kk = i >> 4, dg = (i & 15)*4;
        int k = k0 + kk;
        short4 v = {0,0,0,0};
        if (k < KT) v = *(const short4*)(vf + ((size_t)nh*KT + k)*DD + dg);
        Ts[(dg+0)*65 + kk] = v.x;
        Ts[(dg+1)*65 + kk] = v.y;
        Ts[(dg+2)*65 + kk] = v.z;
        Ts[(dg+3)*65 + kk] = v.w;
    }
    __syncthreads();
    for (int i = tid; i < 1024; i += 256) {
        int d = i >> 4, kg = (i & 15)*4;
        int k = k0 + kg;
        if (k < KT) {
            short4 o;
            o.x = Ts[d*65 + kg+0]; o.y = Ts[d*65 + kg+1];
            o.z = Ts[d*65 + kg+2]; o.w = Ts[d*65 + kg+3];
            *(short4*)(vt + ((size_t)nh*DD + d)*KT + k) = o;
        }
    }
}

// ---------------------------------------------------------------------------
// K2: energy, MFMA NT. grid (17, S/64, BN*HH). E[(n,q),h,k].
// ---------------------------------------------------------------------------
__global__ __launch_bounds__(256) void energy_mfma(
    const short* __restrict__ qf, const short* __restrict__ kf,
    short* __restrict__ E)
{
    __shared__ short Qs[64*72];
    __shared__ short Ks[64*72];
    const int tid = threadIdx.x;
    const int kt = blockIdx.x;
    const int mt = blockIdx.y;
    const int nh = blockIdx.z;
    const int wave = tid >> 6, lane = tid & 63;
    const int lr = lane & 15, lq = lane >> 4;

    for (int i = tid; i < 1024; i += 256) {
        int r = i >> 4, cg = (i & 15)*4;
        *(short4*)(Qs + r*72 + cg) =
            *(const short4*)(qf + ((size_t)nh*SS + mt*64 + r)*DD + cg);
        int kcol = kt*64 + r;
        short4 kv = {0,0,0,0};
        if (kcol < KT) kv = *(const short4*)(kf + ((size_t)nh*KT + kcol)*DD + cg);
        *(short4*)(Ks + r*72 + cg) = kv;
    }
    __syncthreads();

    f32x4 acc[4];
    #pragma unroll
    for (int nt = 0; nt < 4; ++nt) acc[nt] = {0.f,0.f,0.f,0.f};
    #pragma unroll
    for (int ks = 0; ks < 2; ++ks) {
        int ko = ks*32 + lq*8;
        short8 a = *(const short8*)(Qs + (wave*16 + lr)*72 + ko);
        #pragma unroll
        for (int nt = 0; nt < 4; ++nt) {
            short8 b = *(const short8*)(Ks + (nt*16 + lr)*72 + ko);
            acc[nt] = MFMA16(a, b, acc[nt]);
        }
    }
    const int n = nh >> 3, h = nh & 7;
    #pragma unroll
    for (int nt = 0; nt < 4; ++nt) {
        int kcol = kt*64 + nt*16 + lr;
        if (kcol >= KT) continue;
        #pragma unroll
        for (int reg = 0; reg < 4; ++reg) {
            int q = mt*64 + wave*16 + lq*4 + reg;
            E[(((size_t)(n*SS + q))*HH + h)*KT + kcol] = f2s(acc[nt][reg]);
        }
    }
}

// ---------------------------------------------------------------------------
// K3: register-resident softmax. One block per (n,q) row; each thread owns
// k in {tid, tid+256, ...} (5 cols) x 8 heads = 40 floats in regs.
// Wave shuffle reductions + 32B LDS cross-wave combine. LDS ~0.7 KB.
// ---------------------------------------------------------------------------
__global__ __launch_bounds__(256) void softmax_kernel(
    short* __restrict__ E, const int* __restrict__ mask,
    const float* __restrict__ th_pre, const float* __restrict__ th_post)
{
    __shared__ float thp[64], thq[64];
    __shared__ float wred[4][8];
    const int tid = threadIdx.x;
    const int wave = tid >> 6, lane = tid & 63;
    const int blk = blockIdx.x;              // n*SS + q
    const int n = blk >> 10, q = blk & 1023;
    if (tid < 64) { thp[tid] = th_pre[tid]; thq[tid] = th_post[tid]; }
    __syncthreads();
    short* Eb = E + (size_t)blk*HH*KT;

    const float sl[8] = {0.5f,0.25f,0.125f,0.0625f,
                         0.03125f,0.015625f,0.0078125f,0.00390625f};
    const float invs = 0.044194173824159216f;   // 1/sqrt(512)
    const int* mrow = mask + (size_t)n*SS*SS + (size_t)q*SS;

    float tt[5][8];
    float mx[8];
    #pragma unroll
    for (int h = 0; h < 8; ++h) mx[h] = -3.4e38f;

    #pragma unroll
    for (int j = 0; j < 5; ++j) {
        int k = tid + j*256;
        if (k < KT) {
            float dist = (k < SS) ? fabsf((float)(q - k)) : 0.f;
            bool dead = (k < SS) && (mrow[k] == 0);
            float a[8];
            #pragma unroll
            for (int g = 0; g < 8; ++g) a[g] = s2f(Eb[g*KT + k]) - dist*sl[g];
            #pragma unroll
            for (int h = 0; h < 8; ++h) {
                float t = 0.f;
                #pragma unroll
                for (int g = 0; g < 8; ++g) t += thp[h*8 + g]*a[g];
                if (dead) t = -1e4f;
                t *= invs;
                tt[j][h] = t;
                mx[h] = fmaxf(mx[h], t);
            }
        } else {
            #pragma unroll
            for (int h = 0; h < 8; ++h) tt[j][h] = -3.4e38f;
        }
    }
    // wave max reduce
    #pragma unroll
    for (int h = 0; h < 8; ++h) {
        #pragma unroll
        for (int off = 32; off > 0; off >>= 1)
            mx[h] = fmaxf(mx[h], __shfl_xor(mx[h], off));
    }
    if (lane == 0) {
        #pragma unroll
        for (int h = 0; h < 8; ++h) wred[wave][h] = mx[h];
    }
    __syncthreads();
    float mred[8];
    #pragma unroll
    for (int h = 0; h < 8; ++h)
        mred[h] = fmaxf(fmaxf(wred[0][h], wred[1][h]),
                        fmaxf(wred[2][h], wred[3][h]));
    __syncthreads();   // wred reuse below

    float sm[8];
    #pragma unroll
    for (int g = 0; g < 8; ++g) sm[g] = 0.f;
    #pragma unroll
    for (int j = 0; j < 5; ++j) {
        int k = tid + j*256;
        if (k < KT) {
            #pragma unroll
            for (int g = 0; g < 8; ++g) {
                float e = __expf(tt[j][g] - mred[g]);
                tt[j][g] = e;
                sm[g] += e;
            }
        }
    }
    #pragma unroll
    for (int g = 0; g < 8; ++g) {
        #pragma unroll
        for (int off = 32; off > 0; off >>= 1)
            sm[g] += __shfl_xor(sm[g], off);
    }
    if (lane == 0) {
        #pragma unroll
        for (int g = 0; g < 8; ++g) wred[wave][g] = sm[g];
    }
    __syncthreads();
    float lred[8];
    #pragma unroll
    for (int g = 0; g < 8; ++g)
        lred[g] = 1.0f / (wred[0][g] + wred[1][g] + wred[2][g] + wred[3][g]);

    #pragma unroll
    for (int j = 0; j < 5; ++j) {
        int k = tid + j*256;
        if (k < KT) {
            float e[8];
            #pragma unroll
            for (int g = 0; g < 8; ++g) e[g] = tt[j][g]*lred[g];
            #pragma unroll
            for (int h = 0; h < 8; ++h) {
                float t = 0.f;
                #pragma unroll
                for (int g = 0; g < 8; ++g) t += thq[h*8 + g]*e[g];
                Eb[h*KT + k] = f2s(t);
            }
        }
    }
}

// ---------------------------------------------------------------------------
// K4: PV via vt, NT-GEMM, q-tile 32, register-prefetch dbuf. grid (32, 64).
// ---------------------------------------------------------------------------
__device__ __forceinline__ void pv_loadP(const short* __restrict__ E,
    int n, int h, int ql0, int kt, int tid, short4* rp)
{
    #pragma unroll
    for (int j = 0; j < 2; ++j) {
        int i = tid + j*256;
        int r = i >> 4, cg = (i & 15)*4;
        int k = kt*64 + cg;
        short4 v = {0,0,0,0};
        if (k < KT)
            v = *(const short4*)(E + (((size_t)(n*SS + ql0 + r))*HH + h)*KT + k);
        rp[j] = v;
    }
}
__device__ __forceinline__ void pv_loadV(const short* __restrict__ vt,
    int nh, int kt, int tid, short4* rv)
{
    #pragma unroll
    for (int j = 0; j < 4; ++j) {
        int i = tid + j*256;
        int r = i >> 4, cg = (i & 15)*4;
        int k = kt*64 + cg;
        short4 v = {0,0,0,0};
        if (k < KT)
            v = *(const short4*)(vt + ((size_t)nh*DD + r)*KT + k);
        rv[j] = v;
    }
}

__global__ __launch_bounds__(256) void pv_mfma(
    const short* __restrict__ E, const short* __restrict__ vt,
    short* __restrict__ AO)
{
    __shared__ short Ps[32*72];
    __shared__ short Vs[64*72];
    const int tid = threadIdx.x;
    const int ql0 = blockIdx.x * 32;
    const int nh = blockIdx.y;
    const int n = nh >> 3, h = nh & 7;
    const int wave = tid >> 6, lane = tid & 63;
    const int lr = lane & 15, lq = lane >> 4;
    const int mh = wave & 1, nb = (wave >> 1)*32;

    short4 rp[2], rv[4];
    pv_loadP(E, n, h, ql0, 0, tid, rp);
    pv_loadV(vt, nh, 0, tid, rv);

    f32x4 acc[2];
    acc[0] = {0.f,0.f,0.f,0.f}; acc[1] = {0.f,0.f,0.f,0.f};

    for (int kt = 0; kt < 17; ++kt) {
        if (kt) __syncthreads();
        #pragma unroll
        for (int j = 0; j < 2; ++j) {
            int i = tid + j*256;
            *(short4*)(Ps + (i >> 4)*72 + (i & 15)*4) = rp[j];
        }
        #pragma unroll
        for (int j = 0; j < 4; ++j) {
            int i = tid + j*256;
            *(short4*)(Vs + (i >> 4)*72 + (i & 15)*4) = rv[j];
        }
        __syncthreads();
        if (kt + 1 < 17) {
            pv_loadP(E, n, h, ql0, kt+1, tid, rp);
            pv_loadV(vt, nh, kt+1, tid, rv);
        }
        #pragma unroll
        for (int ks = 0; ks < 2; ++ks) {
            int ko = ks*32 + lq*8;
            short8 a = *(const short8*)(Ps + (mh*16 + lr)*72 + ko);
            #pragma unroll
            for (int nt = 0; nt < 2; ++nt) {
                short8 b = *(const short8*)(Vs + (nb + nt*16 + lr)*72 + ko);
                acc[nt] = MFMA16(a, b, acc[nt]);
            }
        }
    }
    #pragma unroll
    for (int nt = 0; nt < 2; ++nt) {
        int d = nb + nt*16 + lr;
        #pragma unroll
        for (int reg = 0; reg < 4; ++reg) {
            int qg = ql0 + mh*16 + lq*4 + reg;
            AO[((size_t)(n*SS) + qg)*CC + h*64 + d] = f2s(acc[nt][reg]);
        }
    }
}

// ---------------------------------------------------------------------------
// K5: fc, 64x64 tile, XCD-swizzled, register-prefetch dbuf. K=512.
// ---------------------------------------------------------------------------
__device__ __forceinline__ void g_load4(const short* __restrict__ src,
    size_t rowstride, int row0, int col0, int tid, short4* r)
{
    #pragma unroll
    for (int j = 0; j < 4; ++j) {
        int i = tid + j*256;
        int rr = i >> 4, cg = (i & 15)*4;
        r[j] = *(const short4*)(src + (size_t)(row0 + rr)*rowstride + col0 + cg);
    }
}
__device__ __forceinline__ void lds_store4(short* __restrict__ dst,
    int tid, const short4* r)
{
    #pragma unroll
    for (int j = 0; j < 4; ++j) {
        int i = tid + j*256;
        *(short4*)(dst + (i >> 4)*72 + (i & 15)*4) = r[j];
    }
}

__global__ __launch_bounds__(256) void fc_mfma(
    const short* __restrict__ A, const short* __restrict__ Bt,
    const float* __restrict__ bias, const float* __restrict__ x,
    short* __restrict__ out)
{
    __shared__ short As[64*72];
    __shared__ short Bs[64*72];
    const int tid = threadIdx.x;
    const int lin = blockIdx.x + 8*blockIdx.y;      // grid (8,128)
    const int xcd = lin & 7, slot = lin >> 3;
    const int m0 = (xcd*16 + (slot & 15))*64;
    const int n0 = (slot >> 4)*64;
    const int wave = tid >> 6, lane = tid & 63;
    const int lr = lane & 15, lq = lane >> 4;

    short4 ra[4], rb[4];
    g_load4(A, CC, m0, 0, tid, ra);
    g_load4(Bt, CC, n0, 0, tid, rb);

    f32x4 acc[4];
    #pragma unroll
    for (int nt = 0; nt < 4; ++nt) acc[nt] = {0.f,0.f,0.f,0.f};

    for (int kt = 0; kt < CC; kt += 64) {
        if (kt) __syncthreads();
        lds_store4(As, tid, ra);
        lds_store4(Bs, tid, rb);
        __syncthreads();
        if (kt + 64 < CC) {
            g_load4(A, CC, m0, kt+64, tid, ra);
            g_load4(Bt, CC, n0, kt+64, tid, rb);
        }
        #pragma unroll
        for (int ks = 0; ks < 2; ++ks) {
            int ko = ks*32 + lq*8;
            short8 a = *(const short8*)(As + (wave*16 + lr)*72 + ko);
            #pragma unroll
            for (int nt = 0; nt < 4; ++nt) {
                short8 b = *(const short8*)(Bs + (nt*16 + lr)*72 + ko);
                acc[nt] = MFMA16(a, b, acc[nt]);
            }
        }
    }
    #pragma unroll
    for (int nt = 0; nt < 4; ++nt) {
        int nn = n0 + nt*16 + lr;
        #pragma unroll
        for (int reg = 0; reg < 4; ++reg) {
            int m = m0 + wave*16 + lq*4 + reg;
            out[(size_t)m*CC + nn] =
                f2s(acc[nt][reg] + bias[nn] + x[(size_t)m*CC + nn]);
        }
    }
}

// ---------------------------------------------------------------------------
// K6: causal conv as NT GEMM K=1536, 64x64, XCD-swizzled, prefetch dbuf.
// ---------------------------------------------------------------------------
__device__ __forceinline__ void conv_loadA(const short* __restrict__ A,
    int m0, int kt, int tid, short4* ra)
{
    const int shift = (kt >> 9) - 2;
    const int ci0 = kt & 511;
    #pragma unroll
    for (int j = 0; j < 4; ++j) {
        int i = tid + j*256;
        int rr = i >> 4, cg = (i & 15)*4;
        int m = m0 + rr;
        int s = m & (SS-1);
        short4 v = {0,0,0,0};
        if (s + shift >= 0)
            v = *(const short4*)(A + (size_t)(m + shift)*CC + ci0 + cg);
        ra[j] = v;
    }
}

__global__ __launch_bounds__(256) void conv_mfma(
    const short* __restrict__ A, const short* __restrict__ Bt,
    const float* __restrict__ bias, short* __restrict__ out)
{
    __shared__ short As[64*72];
    __shared__ short Bs[64*72];
    const int tid = threadIdx.x;
    const int lin = blockIdx.x + 8*blockIdx.y;      // grid (8,128)
    const int xcd = lin & 7, slot = lin >> 3;
    const int m0 = (xcd*16 + (slot & 15))*64;
    const int n0 = (slot >> 4)*64;
    const int wave = tid >> 6, lane = tid & 63;
    const int lr = lane & 15, lq = lane >> 4;

    short4 ra[4], rb[4];
    conv_loadA(A, m0, 0, tid, ra);
    g_load4(Bt, 1536, n0, 0, tid, rb);

    f32x4 acc[4];
    #pragma unroll
    for (int nt = 0; nt < 4; ++nt) acc[nt] = {0.f,0.f,0.f,0.f};

    for (int kt = 0; kt < 1536; kt += 64) {
        if (kt) __syncthreads();
        lds_store4(As, tid, ra);
        lds_store4(Bs, tid, rb);
        __syncthreads();
        if (kt + 64 < 1536) {
            conv_loadA(A, m0, kt+64, tid, ra);
            g_load4(Bt, 1536, n0, kt+64, tid, rb);
        }
        #pragma unroll
        for (int ks = 0; ks < 2; ++ks) {
            int ko = ks*32 + lq*8;
            short8 a = *(const short8*)(As + (wave*16 + lr)*72 + ko);
            #pragma unroll
            for (int nt = 0; nt < 4; ++nt) {
                short8 b = *(const short8*)(Bs + (nt*16 + lr)*72 + ko);
                acc[nt] = MFMA16(a, b, acc[nt]);
            }
        }
    }
    #pragma unroll
    for (int nt = 0; nt < 4; ++nt) {
        int nn = n0 + nt*16 + lr;
        #pragma unroll
        for (int reg = 0; reg < 4; ++reg) {
            int m = m0 + wave*16 + lq*4 + reg;
            float v = acc[nt][reg] + bias[nn];
            out[(size_t)m*CC + nn] = f2s(fmaxf(v, 0.f));
        }
    }
}

// ---------------------------------------------------------------------------
// K7: out = LN(relu(c2 + xres) masked) * g + b.  f32 out.
// ---------------------------------------------------------------------------
__global__ __launch_bounds__(256) void final_kernel(
    const short* __restrict__ c2, const short* __restrict__ xres,
    const int* __restrict__ mask, const float* __restrict__ g,
    const float* __restrict__ b, float* __restrict__ out)
{
    __shared__ float red[256];
    const int tid = threadIdx.x;
    const int m = blockIdx.x;
    const int n = m >> 10, s = m & 1023;
    const int mk = mask[(size_t)n*SS*SS + (size_t)s*SS];

    float v0 = fmaxf(s2f(c2[(size_t)m*CC + tid])       + s2f(xres[(size_t)m*CC + tid]),       0.f);
    float v1 = fmaxf(s2f(c2[(size_t)m*CC + tid + 256]) + s2f(xres[(size_t)m*CC + tid + 256]), 0.f);
    if (mk == 0) { v0 = 0.f; v1 = 0.f; }

    red[tid] = v0 + v1;
    __syncthreads();
    for (int off = 128; off > 0; off >>= 1) {
        if (tid < off) red[tid] += red[tid + off];
        __syncthreads();
    }
    float mu = red[0] * (1.0f/512.0f);
    __syncthreads();
    float d0 = v0 - mu, d1 = v1 - mu;
    red[tid] = d0*d0 + d1*d1;
    __syncthreads();
    for (int off = 128; off > 0; off >>= 1) {
        if (tid < off) red[tid] += red[tid + off];
        __syncthreads();
    }
    float rstd = rsqrtf(red[0] * (1.0f/512.0f) + 1e-5f);
    out[(size_t)m*CC + tid]       = d0*rstd*g[tid]       + b[tid];
    out[(size_t)m*CC + tid + 256] = d1*rstd*g[tid + 256] + b[tid + 256];
}

// ---------------------------------------------------------------------------
extern "C" void kernel_launch(void* const* d_in, const int* in_sizes, int n_in,
                              void* d_out, int out_size, void* d_ws, size_t ws_size,
                              hipStream_t stream)
{
    const float* x      = (const float*)d_in[0];
    const int*   mask   = (const int*)  d_in[1];
    const float* Wq     = (const float*)d_in[2];
    const float* Wk     = (const float*)d_in[3];
    const float* Wv     = (const float*)d_in[4];
    const float* pk     = (const float*)d_in[5];
    const float* pv     = (const float*)d_in[6];
    const float* th_pre = (const float*)d_in[7];
    const float* th_post= (const float*)d_in[8];
    const float* fc_w   = (const float*)d_in[9];
    const float* fc_b   = (const float*)d_in[10];
    const float* c1w    = (const float*)d_in[11];
    const float* c1b    = (const float*)d_in[12];
    const float* c2w    = (const float*)d_in[13];
    const float* c2b    = (const float*)d_in[14];
    const float* lng    = (const float*)d_in[15];
    const float* lnb    = (const float*)d_in[16];
    float* out = (float*)d_out;
    (void)in_sizes; (void)n_in; (void)out_size; (void)ws_size;

    char* ws = (char*)d_ws;
    const size_t SZ_Q  = (size_t)BN*HH*SS*DD*2;    //  8.39 MB
    const size_t SZ_K  = (size_t)BN*HH*KT*DD*2;    //  8.52 MB
    const size_t SZ_VT = (size_t)BN*HH*DD*KT*2;    //  8.52 MB
    const size_t SZ_E  = (size_t)BN*SS*HH*KT*2;    // 136.3 MB (un-chunked)
    const size_t SZ_A  = (size_t)BN*SS*CC*2;       //  8.39 MB

    short* qf  = (short*)(ws);
    short* kf  = (short*)(ws + SZ_Q);
    short* vf  = (short*)(ws + SZ_Q + SZ_K);
    short* vt  = (short*)(ws + SZ_Q + 2*SZ_K);
    short* E   = (short*)(ws + SZ_Q + 2*SZ_K + SZ_VT);
    short* AO  = (short*)(ws + SZ_Q + 2*SZ_K + SZ_VT + SZ_E);
    char*  wend = ws + SZ_Q + 2*SZ_K + SZ_VT + SZ_E + SZ_A;
    short* Bfc = (short*)(wend);
    short* Bc1 = (short*)(wend + 512*512*2);
    short* Bc2 = (short*)(wend + 512*512*2 + 512*1536*2);
    short* Bqkv= (short*)(wend + 512*512*2 + 2*512*1536*2);
    // Aliases (regions dead when these are first written):
    short* xres = qf;   // qf dead after energy
    short* h1   = kf;   // kf dead after energy
    short* c2   = vf;   // vf dead after vtrans (pv uses vt)
    // total ws ~= 182.2 MB  (ws_size >= 256 MiB per harness fill profile)

    {
        int total = 512*512 + 2*512*1536 + 3*64*64;
        prep_kernel<<<(total + 255)/256, 256, 0, stream>>>(
            fc_w, c1w, c2w, Wq, Wk, Wv, Bfc, Bc1, Bc2, Bqkv);
    }
    qkv_mfma<<<dim3(BN*SS/64, HH), 256, 0, stream>>>(x, Bqkv, qf, kf, vf);
    persist_kernel<<<(BN*HH*PP*DD + 255)/256, 256, 0, stream>>>(pk, pv, kf, vf);
    vtrans_kernel<<<dim3(17, BN*HH), 256, 0, stream>>>(vf, vt);

    energy_mfma<<<dim3(17, SS/64, BN*HH), 256, 0, stream>>>(qf, kf, E);
    softmax_kernel<<<BN*SS, 256, 0, stream>>>(E, mask, th_pre, th_post);
    pv_mfma<<<dim3(SS/32, BN*HH), 256, 0, stream>>>(E, vt, AO);

    fc_mfma<<<dim3(8, 128), 256, 0, stream>>>(AO, Bfc, fc_b, x, xres);
    conv_mfma<<<dim3(8, 128), 256, 0, stream>>>(xres, Bc1, c1b, h1);
    conv_mfma<<<dim3(8, 128), 256, 0, stream>>>(h1, Bc2, c2b, c2);
    final_kernel<<<BN*SS, 256, 0, stream>>>(c2, xres, mask, lng, lnb, out);
}

// Round 8
// 399.797 us; speedup vs baseline: 12.9469x; 1.0794x over previous
//
#include <hip/hip_runtime.h>
#include <hip/hip_bf16.h>

#define BN 8
#define SS 1024
#define CC 512
#define HH 8
#define DD 64
#define PP 16
#define KT 1040

typedef __hip_bfloat16 bf16;
typedef __attribute__((ext_vector_type(8))) short short8;
typedef __attribute__((ext_vector_type(4))) float f32x4;
typedef __attribute__((ext_vector_type(2))) float f32x2;

__device__ __forceinline__ short f2s(float v){ bf16 b = __float2bfloat16(v); return *(short*)&b; }
__device__ __forceinline__ float s2f(short s){ bf16 b; *(short*)&b = s; return __bfloat162float(b); }

#define MFMA16(a,b,c) __builtin_amdgcn_mfma_f32_16x16x32_bf16(a,b,c,0,0,0)

// ---------------------------------------------------------------------------
// P0: weight pre-conversion to bf16 NT layouts.
// ---------------------------------------------------------------------------
__global__ __launch_bounds__(256) void prep_kernel(
    const float* __restrict__ fc_w, const float* __restrict__ c1w,
    const float* __restrict__ c2w, const float* __restrict__ Wq,
    const float* __restrict__ Wk, const float* __restrict__ Wv,
    short* __restrict__ Bfc, short* __restrict__ Bc1,
    short* __restrict__ Bc2, short* __restrict__ Bqkv)
{
    int i = blockIdx.x*256 + threadIdx.x;
    const int NFC = 512*512, NCV = 512*1536, NQ = 3*64*64;
    if (i < NFC) { Bfc[i] = f2s(fc_w[i]); return; }
    i -= NFC;
    if (i < NCV) {
        int o = i/1536, r = i%1536, dk = r>>9, ci = r&511;
        Bc1[i] = f2s(c1w[(o*512+ci)*3+dk]); return;
    }
    i -= NCV;
    if (i < NCV) {
        int o = i/1536, r = i%1536, dk = r>>9, ci = r&511;
        Bc2[i] = f2s(c2w[(o*512+ci)*3+dk]); return;
    }
    i -= NCV;
    if (i < NQ) {
        int w = i >> 12, rest = i & 4095;
        const float* W = (w==0)?Wq:(w==1)?Wk:Wv;
        Bqkv[i] = f2s(W[((rest>>6)&63)*64 + (rest&63)]);
    }
}

// ---------------------------------------------------------------------------
// K1: QKV projection, MFMA.
// ---------------------------------------------------------------------------
__global__ __launch_bounds__(256) void qkv_mfma(
    const float* __restrict__ x, const short* __restrict__ Bqkv,
    short* __restrict__ qf, short* __restrict__ kf, short* __restrict__ vf)
{
    __shared__ short Xs[64*72];
    __shared__ short Ws[192*72];
    const int tid = threadIdx.x;
    const int m0 = blockIdx.x * 64;
    const int h = blockIdx.y;
    const int wave = tid >> 6, lane = tid & 63;
    const int lr = lane & 15, lq = lane >> 4;

    for (int i = tid; i < 1024; i += 256) {
        int r = i >> 4, cg = (i & 15)*4;
        float4 v = *(const float4*)(x + (size_t)(m0+r)*CC + h*64 + cg);
        Xs[r*72+cg+0] = f2s(v.x); Xs[r*72+cg+1] = f2s(v.y);
        Xs[r*72+cg+2] = f2s(v.z); Xs[r*72+cg+3] = f2s(v.w);
    }
    for (int i = tid; i < 3072; i += 256) {
        int r = i >> 4, cg = (i & 15)*4;
        *(short4*)(Ws + r*72 + cg) = *(const short4*)(Bqkv + (size_t)r*64 + cg);
    }
    __syncthreads();

    f32x4 acc[12];
    #pragma unroll
    for (int nt = 0; nt < 12; ++nt) acc[nt] = {0.f,0.f,0.f,0.f};
    #pragma unroll
    for (int ks = 0; ks < 2; ++ks) {
        int ko = ks*32 + lq*8;
        short8 a = *(const short8*)(Xs + (wave*16 + lr)*72 + ko);
        #pragma unroll
        for (int nt = 0; nt < 12; ++nt) {
            short8 b = *(const short8*)(Ws + (nt*16 + lr)*72 + ko);
            acc[nt] = MFMA16(a, b, acc[nt]);
        }
    }
    #pragma unroll
    for (int nt = 0; nt < 12; ++nt) {
        int ep = nt*16 + lr;
        int w = ep >> 6, e = ep & 63;
        #pragma unroll
        for (int reg = 0; reg < 4; ++reg) {
            int m = m0 + wave*16 + lq*4 + reg;
            int n = m >> 10, s = m & 1023;
            short v = f2s(acc[nt][reg]);
            if (w == 0)      qf[(((size_t)(n*HH+h))*SS + s)*DD + e] = v;
            else if (w == 1) kf[(((size_t)(n*HH+h))*KT + s)*DD + e] = v;
            else             vf[(((size_t)(n*HH+h))*KT + s)*DD + e] = v;
        }
    }
}

// ---------------------------------------------------------------------------
// K1b: persistent tokens -> kf/vf tail.
// ---------------------------------------------------------------------------
__global__ __launch_bounds__(256) void persist_kernel(
    const float* __restrict__ pk, const float* __restrict__ pv,
    short* __restrict__ kf, short* __restrict__ vf)
{
    int idx = blockIdx.x*256 + threadIdx.x;
    if (idx >= BN*HH*PP*DD) return;
    int d = idx & 63, p = (idx >> 6) & 15, h = (idx >> 10) & 7, n = idx >> 13;
    size_t dst = (((size_t)(n*HH+h))*KT + SS + p)*DD + d;
    size_t src = ((size_t)p*HH + h)*DD + d;
    kf[dst] = f2s(pk[src]);
    vf[dst] = f2s(pv[src]);
}

// ---------------------------------------------------------------------------
// K1c: global V transpose: vt[nh][d][k] = vf[nh][k][d].
// ---------------------------------------------------------------------------
__global__ __launch_bounds__(256) void vtrans_kernel(
    const short* __restrict__ vf, short* __restrict__ vt)
{
    __shared__ short Ts[64*65];
    const int tid = threadIdx.x;
    const int k0 = blockIdx.x * 64;
    const int nh = blockIdx.y;
    for (int i = tid; i < 1024; i += 256) {
        int kk = i >> 4, dg = (i & 15)*4;
        int k = k0 + kk;
        short4 v = {0,0,0,0};
        if (k < KT) v = *(const short4*)(vf + ((size_t)nh*KT + k)*DD + dg);
        Ts[(dg+0)*65 + kk] = v.x;
        Ts[(dg+1)*65 + kk] = v.y;
        Ts[(dg+2)*65 + kk] = v.z;
        Ts[(dg+3)*65 + kk] = v.w;
    }
    __syncthreads();
    for (int i = tid; i < 1024; i += 256) {
        int d = i >> 4, kg = (i & 15)*4;
        int k = k0 + kg;
        if (k < KT) {
            short4 o;
            o.x = Ts[d*65 + kg+0]; o.y = Ts[d*65 + kg+1];
            o.z = Ts[d*65 + kg+2]; o.w = Ts[d*65 + kg+3];
            *(short4*)(vt + ((size_t)nh*DD + d)*KT + k) = o;
        }
    }
}

// ---------------------------------------------------------------------------
// K2: energy, MFMA NT. grid (17, S/64, BN*HH). E[(n,q),h,k].
// ---------------------------------------------------------------------------
__global__ __launch_bounds__(256) void energy_mfma(
    const short* __restrict__ qf, const short* __restrict__ kf,
    short* __restrict__ E)
{
    __shared__ short Qs[64*72];
    __shared__ short Ks[64*72];
    const int tid = threadIdx.x;
    const int kt = blockIdx.x;
    const int mt = blockIdx.y;
    const int nh = blockIdx.z;
    const int wave = tid >> 6, lane = tid & 63;
    const int lr = lane & 15, lq = lane >> 4;

    for (int i = tid; i < 1024; i += 256) {
        int r = i >> 4, cg = (i & 15)*4;
        *(short4*)(Qs + r*72 + cg) =
            *(const short4*)(qf + ((size_t)nh*SS + mt*64 + r)*DD + cg);
        int kcol = kt*64 + r;
        short4 kv = {0,0,0,0};
        if (kcol < KT) kv = *(const short4*)(kf + ((size_t)nh*KT + kcol)*DD + cg);
        *(short4*)(Ks + r*72 + cg) = kv;
    }
    __syncthreads();

    f32x4 acc[4];
    #pragma unroll
    for (int nt = 0; nt < 4; ++nt) acc[nt] = {0.f,0.f,0.f,0.f};
    #pragma unroll
    for (int ks = 0; ks < 2; ++ks) {
        int ko = ks*32 + lq*8;
        short8 a = *(const short8*)(Qs + (wave*16 + lr)*72 + ko);
        #pragma unroll
        for (int nt = 0; nt < 4; ++nt) {
            short8 b = *(const short8*)(Ks + (nt*16 + lr)*72 + ko);
            acc[nt] = MFMA16(a, b, acc[nt]);
        }
    }
    const int n = nh >> 3, h = nh & 7;
    #pragma unroll
    for (int nt = 0; nt < 4; ++nt) {
        int kcol = kt*64 + nt*16 + lr;
        if (kcol >= KT) continue;
        #pragma unroll
        for (int reg = 0; reg < 4; ++reg) {
            int q = mt*64 + wave*16 + lq*4 + reg;
            E[(((size_t)(n*SS + q))*HH + h)*KT + kcol] = f2s(acc[nt][reg]);
        }
    }
}

// ---------------------------------------------------------------------------
// K3: softmax, no-max variant (premixed |t| <= ~51 -> exp/sum safely in f32;
// softmax is shift-invariant). Columns processed as float2 PAIRS (k, k+256)
// so the 8x8 mixes become packed-f32 FMA candidates. Main path (k<1024)
// branch-free; 16 persistent columns are a tail on tid<16. LDS ~0.7 KB.
// ---------------------------------------------------------------------------
__global__ __launch_bounds__(256) void softmax_kernel(
    short* __restrict__ E, const int* __restrict__ mask,
    const float* __restrict__ th_pre, const float* __restrict__ th_post)
{
    __shared__ float thp[64], thq[64];
    __shared__ float wred[4][8];
    const int tid = threadIdx.x;
    const int wave = tid >> 6, lane = tid & 63;
    const int blk = blockIdx.x;              // n*SS + q
    const int n = blk >> 10, q = blk & 1023;
    if (tid < 64) { thp[tid] = th_pre[tid]; thq[tid] = th_post[tid]; }
    __syncthreads();
    short* Eb = E + (size_t)blk*HH*KT;

    const float sl[8] = {0.5f,0.25f,0.125f,0.0625f,
                         0.03125f,0.015625f,0.0078125f,0.00390625f};
    const float invs = 0.044194173824159216f;   // 1/sqrt(512)
    const int* mrow = mask + (size_t)n*SS*SS + (size_t)q*SS;

    f32x2 tp[2][8];     // exp'd premixed scores, column pairs
    float tl[8];        // tail (persistent cols), tid<16 only
    float sm[8];
    #pragma unroll
    for (int g = 0; g < 8; ++g) { sm[g] = 0.f; tl[g] = 0.f; }

    #pragma unroll
    for (int jj = 0; jj < 2; ++jj) {
        const int k0 = tid + jj*512, k1 = k0 + 256;   // both < 1024 always
        f32x2 dist = { fabsf((float)(q - k0)), fabsf((float)(q - k1)) };
        bool dead0 = (mrow[k0] == 0), dead1 = (mrow[k1] == 0);
        f32x2 a[8];
        #pragma unroll
        for (int g = 0; g < 8; ++g) {
            a[g].x = s2f(Eb[g*KT + k0]) - dist.x*sl[g];
            a[g].y = s2f(Eb[g*KT + k1]) - dist.y*sl[g];
        }
        #pragma unroll
        for (int h = 0; h < 8; ++h) {
            f32x2 t = {0.f, 0.f};
            #pragma unroll
            for (int g = 0; g < 8; ++g) {
                float c = thp[h*8 + g];
                t.x = fmaf(c, a[g].x, t.x);
                t.y = fmaf(c, a[g].y, t.y);
            }
            if (dead0) t.x = -1e4f;
            if (dead1) t.y = -1e4f;
            f32x2 e;
            e.x = __expf(t.x * invs);
            e.y = __expf(t.y * invs);
            tp[jj][h] = e;
            sm[h] += e.x + e.y;
        }
    }
    // tail: persistent keys (no ALiBi, mask padded 1)
    if (tid < 16) {
        const int k = 1024 + tid;
        float a[8];
        #pragma unroll
        for (int g = 0; g < 8; ++g) a[g] = s2f(Eb[g*KT + k]);
        #pragma unroll
        for (int h = 0; h < 8; ++h) {
            float t = 0.f;
            #pragma unroll
            for (int g = 0; g < 8; ++g) t = fmaf(thp[h*8 + g], a[g], t);
            float e = __expf(t * invs);
            tl[h] = e;
            sm[h] += e;
        }
    }
    // sum reduce: wave shuffle + cross-wave combine
    #pragma unroll
    for (int g = 0; g < 8; ++g) {
        #pragma unroll
        for (int off = 32; off > 0; off >>= 1)
            sm[g] += __shfl_xor(sm[g], off);
    }
    if (lane == 0) {
        #pragma unroll
        for (int g = 0; g < 8; ++g) wred[wave][g] = sm[g];
    }
    __syncthreads();
    float lred[8];
    #pragma unroll
    for (int g = 0; g < 8; ++g)
        lred[g] = 1.0f / (wred[0][g] + wred[1][g] + wred[2][g] + wred[3][g]);

    // postmix (1/l folded) + store
    #pragma unroll
    for (int jj = 0; jj < 2; ++jj) {
        const int k0 = tid + jj*512, k1 = k0 + 256;
        f32x2 e[8];
        #pragma unroll
        for (int g = 0; g < 8; ++g) {
            e[g].x = tp[jj][g].x * lred[g];
            e[g].y = tp[jj][g].y * lred[g];
        }
        #pragma unroll
        for (int h = 0; h < 8; ++h) {
            f32x2 t = {0.f, 0.f};
            #pragma unroll
            for (int g = 0; g < 8; ++g) {
                float c = thq[h*8 + g];
                t.x = fmaf(c, e[g].x, t.x);
                t.y = fmaf(c, e[g].y, t.y);
            }
            Eb[h*KT + k0] = f2s(t.x);
            Eb[h*KT + k1] = f2s(t.y);
        }
    }
    if (tid < 16) {
        const int k = 1024 + tid;
        float e[8];
        #pragma unroll
        for (int g = 0; g < 8; ++g) e[g] = tl[g] * lred[g];
        #pragma unroll
        for (int h = 0; h < 8; ++h) {
            float t = 0.f;
            #pragma unroll
            for (int g = 0; g < 8; ++g) t = fmaf(thq[h*8 + g], e[g], t);
            Eb[h*KT + k] = f2s(t);
        }
    }
}

// ---------------------------------------------------------------------------
// K4: PV via vt, NT-GEMM, q-tile 32, register-prefetch dbuf. grid (32, 64).
// ---------------------------------------------------------------------------
__device__ __forceinline__ void pv_loadP(const short* __restrict__ E,
    int n, int h, int ql0, int kt, int tid, short4* rp)
{
    #pragma unroll
    for (int j = 0; j < 2; ++j) {
        int i = tid + j*256;
        int r = i >> 4, cg = (i & 15)*4;
        int k = kt*64 + cg;
        short4 v = {0,0,0,0};
        if (k < KT)
            v = *(const short4*)(E + (((size_t)(n*SS + ql0 + r))*HH + h)*KT + k);
        rp[j] = v;
    }
}
__device__ __forceinline__ void pv_loadV(const short* __restrict__ vt,
    int nh, int kt, int tid, short4* rv)
{
    #pragma unroll
    for (int j = 0; j < 4; ++j) {
        int i = tid + j*256;
        int r = i >> 4, cg = (i & 15)*4;
        int k = kt*64 + cg;
        short4 v = {0,0,0,0};
        if (k < KT)
            v = *(const short4*)(vt + ((size_t)nh*DD + r)*KT + k);
        rv[j] = v;
    }
}

__global__ __launch_bounds__(256) void pv_mfma(
    const short* __restrict__ E, const short* __restrict__ vt,
    short* __restrict__ AO)
{
    __shared__ short Ps[32*72];
    __shared__ short Vs[64*72];
    const int tid = threadIdx.x;
    const int ql0 = blockIdx.x * 32;
    const int nh = blockIdx.y;
    const int n = nh >> 3, h = nh & 7;
    const int wave = tid >> 6, lane = tid & 63;
    const int lr = lane & 15, lq = lane >> 4;
    const int mh = wave & 1, nb = (wave >> 1)*32;

    short4 rp[2], rv[4];
    pv_loadP(E, n, h, ql0, 0, tid, rp);
    pv_loadV(vt, nh, 0, tid, rv);

    f32x4 acc[2];
    acc[0] = {0.f,0.f,0.f,0.f}; acc[1] = {0.f,0.f,0.f,0.f};

    for (int kt = 0; kt < 17; ++kt) {
        if (kt) __syncthreads();
        #pragma unroll
        for (int j = 0; j < 2; ++j) {
            int i = tid + j*256;
            *(short4*)(Ps + (i >> 4)*72 + (i & 15)*4) = rp[j];
        }
        #pragma unroll
        for (int j = 0; j < 4; ++j) {
            int i = tid + j*256;
            *(short4*)(Vs + (i >> 4)*72 + (i & 15)*4) = rv[j];
        }
        __syncthreads();
        if (kt + 1 < 17) {
            pv_loadP(E, n, h, ql0, kt+1, tid, rp);
            pv_loadV(vt, nh, kt+1, tid, rv);
        }
        #pragma unroll
        for (int ks = 0; ks < 2; ++ks) {
            int ko = ks*32 + lq*8;
            short8 a = *(const short8*)(Ps + (mh*16 + lr)*72 + ko);
            #pragma unroll
            for (int nt = 0; nt < 2; ++nt) {
                short8 b = *(const short8*)(Vs + (nb + nt*16 + lr)*72 + ko);
                acc[nt] = MFMA16(a, b, acc[nt]);
            }
        }
    }
    #pragma unroll
    for (int nt = 0; nt < 2; ++nt) {
        int d = nb + nt*16 + lr;
        #pragma unroll
        for (int reg = 0; reg < 4; ++reg) {
            int qg = ql0 + mh*16 + lq*4 + reg;
            AO[((size_t)(n*SS) + qg)*CC + h*64 + d] = f2s(acc[nt][reg]);
        }
    }
}

// ---------------------------------------------------------------------------
// K5: fc, 64x64 tile, XCD-swizzled, register-prefetch dbuf. K=512.
// ---------------------------------------------------------------------------
__device__ __forceinline__ void g_load4(const short* __restrict__ src,
    size_t rowstride, int row0, int col0, int tid, short4* r)
{
    #pragma unroll
    for (int j = 0; j < 4; ++j) {
        int i = tid + j*256;
        int rr = i >> 4, cg = (i & 15)*4;
        r[j] = *(const short4*)(src + (size_t)(row0 + rr)*rowstride + col0 + cg);
    }
}
__device__ __forceinline__ void lds_store4(short* __restrict__ dst,
    int tid, const short4* r)
{
    #pragma unroll
    for (int j = 0; j < 4; ++j) {
        int i = tid + j*256;
        *(short4*)(dst + (i >> 4)*72 + (i & 15)*4) = r[j];
    }
}

__global__ __launch_bounds__(256) void fc_mfma(
    const short* __restrict__ A, const short* __restrict__ Bt,
    const float* __restrict__ bias, const float* __restrict__ x,
    short* __restrict__ out)
{
    __shared__ short As[64*72];
    __shared__ short Bs[64*72];
    const int tid = threadIdx.x;
    const int lin = blockIdx.x + 8*blockIdx.y;      // grid (8,128)
    const int xcd = lin & 7, slot = lin >> 3;
    const int m0 = (xcd*16 + (slot & 15))*64;
    const int n0 = (slot >> 4)*64;
    const int wave = tid >> 6, lane = tid & 63;
    const int lr = lane & 15, lq = lane >> 4;

    short4 ra[4], rb[4];
    g_load4(A, CC, m0, 0, tid, ra);
    g_load4(Bt, CC, n0, 0, tid, rb);

    f32x4 acc[4];
    #pragma unroll
    for (int nt = 0; nt < 4; ++nt) acc[nt] = {0.f,0.f,0.f,0.f};

    for (int kt = 0; kt < CC; kt += 64) {
        if (kt) __syncthreads();
        lds_store4(As, tid, ra);
        lds_store4(Bs, tid, rb);
        __syncthreads();
        if (kt + 64 < CC) {
            g_load4(A, CC, m0, kt+64, tid, ra);
            g_load4(Bt, CC, n0, kt+64, tid, rb);
        }
        #pragma unroll
        for (int ks = 0; ks < 2; ++ks) {
            int ko = ks*32 + lq*8;
            short8 a = *(const short8*)(As + (wave*16 + lr)*72 + ko);
            #pragma unroll
            for (int nt = 0; nt < 4; ++nt) {
                short8 b = *(const short8*)(Bs + (nt*16 + lr)*72 + ko);
                acc[nt] = MFMA16(a, b, acc[nt]);
            }
        }
    }
    #pragma unroll
    for (int nt = 0; nt < 4; ++nt) {
        int nn = n0 + nt*16 + lr;
        #pragma unroll
        for (int reg = 0; reg < 4; ++reg) {
            int m = m0 + wave*16 + lq*4 + reg;
            out[(size_t)m*CC + nn] =
                f2s(acc[nt][reg] + bias[nn] + x[(size_t)m*CC + nn]);
        }
    }
}

// ---------------------------------------------------------------------------
// K6: causal conv as NT GEMM K=1536, 64x64, XCD-swizzled, prefetch dbuf.
// ---------------------------------------------------------------------------
__device__ __forceinline__ void conv_loadA(const short* __restrict__ A,
    int m0, int kt, int tid, short4* ra)
{
    const int shift = (kt >> 9) - 2;
    const int ci0 = kt & 511;
    #pragma unroll
    for (int j = 0; j < 4; ++j) {
        int i = tid + j*256;
        int rr = i >> 4, cg = (i & 15)*4;
        int m = m0 + rr;
        int s = m & (SS-1);
        short4 v = {0,0,0,0};
        if (s + shift >= 0)
            v = *(const short4*)(A + (size_t)(m + shift)*CC + ci0 + cg);
        ra[j] = v;
    }
}

__global__ __launch_bounds__(256) void conv_mfma(
    const short* __restrict__ A, const short* __restrict__ Bt,
    const float* __restrict__ bias, short* __restrict__ out)
{
    __shared__ short As[64*72];
    __shared__ short Bs[64*72];
    const int tid = threadIdx.x;
    const int lin = blockIdx.x + 8*blockIdx.y;      // grid (8,128)
    const int xcd = lin & 7, slot = lin >> 3;
    const int m0 = (xcd*16 + (slot & 15))*64;
    const int n0 = (slot >> 4)*64;
    const int wave = tid >> 6, lane = tid & 63;
    const int lr = lane & 15, lq = lane >> 4;

    short4 ra[4], rb[4];
    conv_loadA(A, m0, 0, tid, ra);
    g_load4(Bt, 1536, n0, 0, tid, rb);

    f32x4 acc[4];
    #pragma unroll
    for (int nt = 0; nt < 4; ++nt) acc[nt] = {0.f,0.f,0.f,0.f};

    for (int kt = 0; kt < 1536; kt += 64) {
        if (kt) __syncthreads();
        lds_store4(As, tid, ra);
        lds_store4(Bs, tid, rb);
        __syncthreads();
        if (kt + 64 < 1536) {
            conv_loadA(A, m0, kt+64, tid, ra);
            g_load4(Bt, 1536, n0, kt+64, tid, rb);
        }
        #pragma unroll
        for (int ks = 0; ks < 2; ++ks) {
            int ko = ks*32 + lq*8;
            short8 a = *(const short8*)(As + (wave*16 + lr)*72 + ko);
            #pragma unroll
            for (int nt = 0; nt < 4; ++nt) {
                short8 b = *(const short8*)(Bs + (nt*16 + lr)*72 + ko);
                acc[nt] = MFMA16(a, b, acc[nt]);
            }
        }
    }
    #pragma unroll
    for (int nt = 0; nt < 4; ++nt) {
        int nn = n0 + nt*16 + lr;
        #pragma unroll
        for (int reg = 0; reg < 4; ++reg) {
            int m = m0 + wave*16 + lq*4 + reg;
            float v = acc[nt][reg] + bias[nn];
            out[(size_t)m*CC + nn] = f2s(fmaxf(v, 0.f));
        }
    }
}

// ---------------------------------------------------------------------------
// K7: out = LN(relu(c2 + xres) masked) * g + b.  f32 out.
// ---------------------------------------------------------------------------
__global__ __launch_bounds__(256) void final_kernel(
    const short* __restrict__ c2, const short* __restrict__ xres,
    const int* __restrict__ mask, const float* __restrict__ g,
    const float* __restrict__ b, float* __restrict__ out)
{
    __shared__ float red[256];
    const int tid = threadIdx.x;
    const int m = blockIdx.x;
    const int n = m >> 10, s = m & 1023;
    const int mk = mask[(size_t)n*SS*SS + (size_t)s*SS];

    float v0 = fmaxf(s2f(c2[(size_t)m*CC + tid])       + s2f(xres[(size_t)m*CC + tid]),       0.f);
    float v1 = fmaxf(s2f(c2[(size_t)m*CC + tid + 256]) + s2f(xres[(size_t)m*CC + tid + 256]), 0.f);
    if (mk == 0) { v0 = 0.f; v1 = 0.f; }

    red[tid] = v0 + v1;
    __syncthreads();
    for (int off = 128; off > 0; off >>= 1) {
        if (tid < off) red[tid] += red[tid + off];
        __syncthreads();
    }
    float mu = red[0] * (1.0f/512.0f);
    __syncthreads();
    float d0 = v0 - mu, d1 = v1 - mu;
    red[tid] = d0*d0 + d1*d1;
    __syncthreads();
    for (int off = 128; off > 0; off >>= 1) {
        if (tid < off) red[tid] += red[tid + off];
        __syncthreads();
    }
    float rstd = rsqrtf(red[0] * (1.0f/512.0f) + 1e-5f);
    out[(size_t)m*CC + tid]       = d0*rstd*g[tid]       + b[tid];
    out[(size_t)m*CC + tid + 256] = d1*rstd*g[tid + 256] + b[tid + 256];
}

// ---------------------------------------------------------------------------
extern "C" void kernel_launch(void* const* d_in, const int* in_sizes, int n_in,
                              void* d_out, int out_size, void* d_ws, size_t ws_size,
                              hipStream_t stream)
{
    const float* x      = (const float*)d_in[0];
    const int*   mask   = (const int*)  d_in[1];
    const float* Wq     = (const float*)d_in[2];
    const float* Wk     = (const float*)d_in[3];
    const float* Wv     = (const float*)d_in[4];
    const float* pk     = (const float*)d_in[5];
    const float* pv     = (const float*)d_in[6];
    const float* th_pre = (const float*)d_in[7];
    const float* th_post= (const float*)d_in[8];
    const float* fc_w   = (const float*)d_in[9];
    const float* fc_b   = (const float*)d_in[10];
    const float* c1w    = (const float*)d_in[11];
    const float* c1b    = (const float*)d_in[12];
    const float* c2w    = (const float*)d_in[13];
    const float* c2b    = (const float*)d_in[14];
    const float* lng    = (const float*)d_in[15];
    const float* lnb    = (const float*)d_in[16];
    float* out = (float*)d_out;
    (void)in_sizes; (void)n_in; (void)out_size; (void)ws_size;

    char* ws = (char*)d_ws;
    const size_t SZ_Q  = (size_t)BN*HH*SS*DD*2;    //  8.39 MB
    const size_t SZ_K  = (size_t)BN*HH*KT*DD*2;    //  8.52 MB
    const size_t SZ_VT = (size_t)BN*HH*DD*KT*2;    //  8.52 MB
    const size_t SZ_E  = (size_t)BN*SS*HH*KT*2;    // 136.3 MB
    const size_t SZ_A  = (size_t)BN*SS*CC*2;       //  8.39 MB

    short* qf  = (short*)(ws);
    short* kf  = (short*)(ws + SZ_Q);
    short* vf  = (short*)(ws + SZ_Q + SZ_K);
    short* vt  = (short*)(ws + SZ_Q + 2*SZ_K);
    short* E   = (short*)(ws + SZ_Q + 2*SZ_K + SZ_VT);
    short* AO  = (short*)(ws + SZ_Q + 2*SZ_K + SZ_VT + SZ_E);
    char*  wend = ws + SZ_Q + 2*SZ_K + SZ_VT + SZ_E + SZ_A;
    short* Bfc = (short*)(wend);
    short* Bc1 = (short*)(wend + 512*512*2);
    short* Bc2 = (short*)(wend + 512*512*2 + 512*1536*2);
    short* Bqkv= (short*)(wend + 512*512*2 + 2*512*1536*2);
    short* xres = qf;
    short* h1   = kf;
    short* c2   = vf;
    // total ws ~= 182.2 MB

    {
        int total = 512*512 + 2*512*1536 + 3*64*64;
        prep_kernel<<<(total + 255)/256, 256, 0, stream>>>(
            fc_w, c1w, c2w, Wq, Wk, Wv, Bfc, Bc1, Bc2, Bqkv);
    }
    qkv_mfma<<<dim3(BN*SS/64, HH), 256, 0, stream>>>(x, Bqkv, qf, kf, vf);
    persist_kernel<<<(BN*HH*PP*DD + 255)/256, 256, 0, stream>>>(pk, pv, kf, vf);
    vtrans_kernel<<<dim3(17, BN*HH), 256, 0, stream>>>(vf, vt);

    energy_mfma<<<dim3(17, SS/64, BN*HH), 256, 0, stream>>>(qf, kf, E);
    softmax_kernel<<<BN*SS, 256, 0, stream>>>(E, mask, th_pre, th_post);
    pv_mfma<<<dim3(SS/32, BN*HH), 256, 0, stream>>>(E, vt, AO);

    fc_mfma<<<dim3(8, 128), 256, 0, stream>>>(AO, Bfc, fc_b, x, xres);
    conv_mfma<<<dim3(8, 128), 256, 0, stream>>>(xres, Bc1, c1b, h1);
    conv_mfma<<<dim3(8, 128), 256, 0, stream>>>(h1, Bc2, c2b, c2);
    final_kernel<<<BN*SS, 256, 0, stream>>>(c2, xres, mask, lng, lnb, out);
}